// Round 8
// baseline (501.032 us; speedup 1.0000x reference)
//
#include <hip/hip_runtime.h>
#include <hip/hip_bf16.h>

typedef unsigned int u32;
typedef unsigned short u16;
typedef __attribute__((ext_vector_type(8))) short frag8;   // 8 bf16 (4 VGPRs)
typedef __attribute__((ext_vector_type(4))) float f32x4;   // MFMA C/D

#define NNODE 100000
#define NVAR  60000
#define NCON  40000
#define NEDGE 500000
#define SLOTCAP 32
#define VAR_BLOCKS 469   // ceil(60000/128)
#define CON_BLOCKS 313   // ceil(40000/128)
#define SPAD 136         // padded S row stride (u16): 272B -> 4-bank skew

// prep-region offsets (u16 units) within wp
// per-layer node image: W1 hi/lo frags 0..15, WCV(128x64 = [Wc_pad;Wv]) hi/lo frags 16..47
#define WP_NODE(l)  ((l) * 24576)
#define WP_VARW2    98304
#define WP_CONW2    106496
#define WP_FC1(ph)  (114688 + (ph) * 20480)
#define WP_FC2      155648
#define WP_FC3      163840
#define PREP_TOTAL  86016

// ---- helpers -------------------------------------------------------------
__device__ __forceinline__ u16 f2bf(float f) {
  u32 u = __float_as_uint(f);
  u32 r = (u + 0x7fffu + ((u >> 16) & 1u)) >> 16;   // RNE
  return (u16)r;
}
__device__ __forceinline__ float bf2f(u16 u) { return __uint_as_float(((u32)u) << 16); }
__device__ __forceinline__ float cvlo(u32 p) { return __uint_as_float(p << 16); }
__device__ __forceinline__ float cvhi(u32 p) { return __uint_as_float(p & 0xffff0000u); }
__device__ __forceinline__ float sigmoidf_(float x) {
  return __builtin_amdgcn_rcpf(1.0f + __expf(-x));
}

// ---- k_prep: format all weight matrices into hi/lo MFMA fragment images --
// frag image layout: frag*512 + lane*8 + j  (lane = (n&15)|(((k&31)>>3)<<4), j=k&7)
__global__ __launch_bounds__(256) void k_prep(
    const float* __restrict__ hw1, const float* __restrict__ wco,
    const float* __restrict__ wva, const float* __restrict__ vw2,
    const float* __restrict__ cw2, const float* __restrict__ f1w,
    const float* __restrict__ f2w, const float* __restrict__ f3w,
    u16* __restrict__ wp)
{
  int g = blockIdx.x * 256 + threadIdx.x;
  if (g >= PREP_TOTAL) return;
  float w; u16* base; int k, n, fr_hi, fr_lo;
  if (g < 49152) {                               // per-layer: W1 (4096) + WCV (8192)
    int l = g / 12288, e = g % 12288;
    base = wp + WP_NODE(l);
    if (e < 4096) {                              // W1 (64x64)
      k = e >> 6; n = e & 63;
      w = hw1[l * 4096 + e];
      int ksp = k >> 5, nt = n >> 4;
      fr_hi = ksp * 4 + nt;                      // 0..7
      fr_lo = (2 + ksp) * 4 + nt;                // 8..15
    } else {                                     // WCV (128x64): rows 0..63 Wc_pad, 64..127 Wv
      int e2 = e - 4096;
      int kk = e2 >> 6; n = e2 & 63;
      if (kk < 64) w = (kk < 62 && n < 62) ? wco[l * 3844 + kk * 62 + n] : 0.f;
      else         w = wva[l * 4096 + (kk - 64) * 64 + n];
      k = kk;
      int kkp = kk >> 5, nt = n >> 4;
      fr_hi = 16 + kkp * 4 + nt;                 // 16..31
      fr_lo = 16 + (4 + kkp) * 4 + nt;           // 32..47
    }
  } else if (g < 53248) {                        // var w2 (62x62 padded)
    int idx = g - 49152; k = idx >> 6; n = idx & 63;
    w = (k < 62 && n < 62) ? vw2[k * 62 + n] : 0.f;
    base = wp + WP_VARW2;
    int ksp = k >> 5, nt = n >> 4;
    fr_hi = ksp * 4 + nt; fr_lo = (2 + ksp) * 4 + nt;
  } else if (g < 57344) {                        // con w2 (63x63 padded)
    int idx = g - 53248; k = idx >> 6; n = idx & 63;
    w = (k < 63 && n < 63) ? cw2[k * 63 + n] : 0.f;
    base = wp + WP_CONW2;
    int ksp = k >> 5, nt = n >> 4;
    fr_hi = ksp * 4 + nt; fr_lo = (2 + ksp) * 4 + nt;
  } else if (g < 77824) {                        // fc1 (320x64), 2 phases
    int e = g - 57344; int kk = e >> 6; n = e & 63;
    int ph = (kk >= 160); k = kk - ph * 160;
    w = f1w[(size_t)kk * 64 + n];
    base = wp + WP_FC1(ph);
    int ksp = k >> 5, nt = n >> 4;
    fr_hi = ksp * 4 + nt; fr_lo = (5 + ksp) * 4 + nt;
  } else if (g < 81920) {                        // fc2 (64x64)
    int idx = g - 77824; k = idx >> 6; n = idx & 63;
    w = f2w[idx];
    base = wp + WP_FC2;
    int ksp = k >> 5, nt = n >> 4;
    fr_hi = ksp * 4 + nt; fr_lo = (2 + ksp) * 4 + nt;
  } else {                                       // fc3 (64x64)
    int idx = g - 81920; k = idx >> 6; n = idx & 63;
    w = f3w[idx];
    base = wp + WP_FC3;
    int ksp = k >> 5, nt = n >> 4;
    fr_hi = ksp * 4 + nt; fr_lo = (2 + ksp) * 4 + nt;
  }
  u16 hi = f2bf(w);
  u16 lo = f2bf(w - bf2f(hi));
  int lane = (n & 15) | (((k & 31) >> 3) << 4);
  int j = k & 7;
  base[fr_hi * 512 + lane * 8 + j] = hi;
  base[fr_lo * 512 + lane * 8 + j] = lo;
}

// ---- fused var+con init (MFMA, transposed) + cnt zeroing -----------------
__global__ __launch_bounds__(256) void k_init(
    const float* __restrict__ vf, const float* __restrict__ cf,
    const int* __restrict__ avar, const int* __restrict__ acon,
    const float* __restrict__ vw1, const float* __restrict__ vb1, const float* __restrict__ vb2,
    const float* __restrict__ cw1, const float* __restrict__ cb1, const float* __restrict__ cb2,
    const u16* __restrict__ wp, u16* __restrict__ x0, int* __restrict__ cnt)
{
  for (int i = blockIdx.x * 256 + threadIdx.x; i < NNODE; i += gridDim.x * 256) cnt[i] = 0;

  const bool isVar = blockIdx.x < VAR_BLOCKS;
  const int bbase = isVar ? blockIdx.x : (blockIdx.x - VAR_BLOCKS);
  const int nItems = isVar ? NVAR : NCON;
  const int KD = isVar ? 62 : 63;
  const float* in  = isVar ? vf : cf;
  const int*   asc = isVar ? avar : acon;
  const float* w1  = isVar ? vw1 : cw1;
  const float* b1  = isVar ? vb1 : cb1;
  const float* b2  = isVar ? vb2 : cb2;
  const u16*   src = wp + (isVar ? WP_VARW2 : WP_CONW2);

  __shared__ u16 sB[16 * 512];
  __shared__ float sw1[64], sb1[64], sb2[64];
  {
    const uint4* s4 = reinterpret_cast<const uint4*>(src);
    uint4* d4 = reinterpret_cast<uint4*>(sB);
    for (int i = threadIdx.x; i < 1024; i += 256) d4[i] = s4[i];
  }
  if (threadIdx.x < 64) {
    int t = threadIdx.x;
    sw1[t] = (t < KD) ? w1[t] : 0.f;
    sb1[t] = (t < KD) ? b1[t] : 0.f;
    sb2[t] = (t < KD) ? b2[t] : 0.f;
  }
  __syncthreads();

  int wid = threadIdx.x >> 6, lane = threadIdx.x & 63;
  long ib = ((long)bbase * 4 + wid) * 32;
  if (ib >= nItems) return;
  int l15 = lane & 15, lg = lane >> 4;

  float w1r[16], b1r[16];
#pragma unroll
  for (int ks = 0; ks < 2; ++ks)
#pragma unroll
    for (int j = 0; j < 8; ++j) {
      int k = 32 * ks + 8 * lg + j;
      w1r[ks * 8 + j] = sw1[k]; b1r[ks * 8 + j] = sb1[k];
    }

  float v0 = in[ib + l15], v1 = in[ib + 16 + l15];
  frag8 hh[2][2], hl[2][2];
#pragma unroll
  for (int np = 0; np < 2; ++np) {
    float v = np ? v1 : v0;
#pragma unroll
    for (int ks = 0; ks < 2; ++ks) {
      frag8 th, tl;
#pragma unroll
      for (int j = 0; j < 8; ++j) {
        float h = fmaxf(fmaf(v, w1r[ks * 8 + j], b1r[ks * 8 + j]), 0.f);
        u16 hi = f2bf(h);
        u16 lo = f2bf(h - bf2f(hi));
        th[j] = (short)hi; tl[j] = (short)lo;
      }
      hh[np][ks] = th; hl[np][ks] = tl;
    }
  }

  const f32x4 z = {0.f, 0.f, 0.f, 0.f};
  f32x4 acc[4][2];
#pragma unroll
  for (int m = 0; m < 4; ++m)
#pragma unroll
    for (int np = 0; np < 2; ++np) acc[m][np] = z;

#pragma unroll
  for (int ks = 0; ks < 2; ++ks)
#pragma unroll
    for (int m = 0; m < 4; ++m) {
      frag8 bh = *reinterpret_cast<const frag8*>(&sB[((ks * 4 + m) * 512) + lane * 8]);
      frag8 bl = *reinterpret_cast<const frag8*>(&sB[(((2 + ks) * 4 + m) * 512) + lane * 8]);
#pragma unroll
      for (int np = 0; np < 2; ++np) {
        acc[m][np] = __builtin_amdgcn_mfma_f32_16x16x32_bf16(bh, hh[np][ks], acc[m][np], 0, 0, 0);
        acc[m][np] = __builtin_amdgcn_mfma_f32_16x16x32_bf16(bh, hl[np][ks], acc[m][np], 0, 0, 0);
        acc[m][np] = __builtin_amdgcn_mfma_f32_16x16x32_bf16(bl, hh[np][ks], acc[m][np], 0, 0, 0);
      }
    }

#pragma unroll
  for (int np = 0; np < 2; ++np) {
    long r = asc[ib + 16 * np + l15];
    float vv = np ? v1 : v0;
    u16* orow = x0 + r * 64;
#pragma unroll
    for (int m = 0; m < 4; ++m) {
      float o[4];
#pragma unroll
      for (int rr = 0; rr < 4; ++rr) o[rr] = acc[m][np][rr] + sb2[16 * m + 4 * lg + rr];
      if (m == 3 && lg == 3) {
        if (isVar) { o[2] = vv; o[3] = 1.0f; } else { o[3] = vv; }
      }
      u32 p0 = (u32)f2bf(o[0]) | ((u32)f2bf(o[1]) << 16);
      u32 p1 = (u32)f2bf(o[2]) | ((u32)f2bf(o[3]) << 16);
      *reinterpret_cast<uint2*>(orow + 16 * m + 4 * lg) = make_uint2(p0, p1);
    }
  }
}

// ---- CSR-ish bucket build: slots[d][pos] = src | (type<<20) --------------
__global__ __launch_bounds__(256) void k_scatter(
    const int* __restrict__ src, const int* __restrict__ dst,
    const int* __restrict__ et, int* __restrict__ cnt, int* __restrict__ slots)
{
  int e = blockIdx.x * 256 + threadIdx.x;
  if (e >= NEDGE) return;
  int d = dst[e];
  int pos = atomicAdd(&cnt[d], 1);
  if (pos < SLOTCAP) slots[d * SLOTCAP + pos] = src[e] | ((et[e] & 1) << 20);
}

// ---- per-layer gate: va[n] = (sigmoid(x@W1+b1).w2+b2)*ef[n] --------------
__global__ __launch_bounds__(256) void k_gate(
    const u16* __restrict__ x, const float* __restrict__ ef,
    const u16* __restrict__ wsrc,     // W1 frags (0..15)
    const float* __restrict__ b1, const float* __restrict__ w2,
    const float* __restrict__ b2, float* __restrict__ va)
{
  __shared__ u16 sB[16 * 512];
  __shared__ float sb1[64], sw2[64];
  {
    const uint4* s4 = reinterpret_cast<const uint4*>(wsrc);
    uint4* d4 = reinterpret_cast<uint4*>(sB);
    for (int i = threadIdx.x; i < 1024; i += 256) d4[i] = s4[i];
  }
  if (threadIdx.x < 64) { sb1[threadIdx.x] = b1[threadIdx.x]; sw2[threadIdx.x] = w2[threadIdx.x]; }
  __syncthreads();

  int wid = threadIdx.x >> 6, lane = threadIdx.x & 63;
  long nb = ((long)blockIdx.x * 4 + wid) * 32;
  if (nb >= NNODE) return;
  int l15 = lane & 15, lg = lane >> 4;

  frag8 xf[2][2];
#pragma unroll
  for (int np = 0; np < 2; ++np) {
    const u16* base = x + (nb + 16 * np + l15) * 64 + 8 * lg;
    xf[np][0] = *reinterpret_cast<const frag8*>(base);
    xf[np][1] = *reinterpret_cast<const frag8*>(base + 32);
  }

  const f32x4 z = {0.f, 0.f, 0.f, 0.f};
  f32x4 acc[4][2];
#pragma unroll
  for (int m = 0; m < 4; ++m)
#pragma unroll
    for (int np = 0; np < 2; ++np) acc[m][np] = z;

#pragma unroll
  for (int ks = 0; ks < 2; ++ks)
#pragma unroll
    for (int m = 0; m < 4; ++m) {
      frag8 bh = *reinterpret_cast<const frag8*>(&sB[((ks * 4 + m) * 512) + lane * 8]);
      frag8 bl = *reinterpret_cast<const frag8*>(&sB[(((2 + ks) * 4 + m) * 512) + lane * 8]);
#pragma unroll
      for (int np = 0; np < 2; ++np) {
        acc[m][np] = __builtin_amdgcn_mfma_f32_16x16x32_bf16(bh, xf[np][ks], acc[m][np], 0, 0, 0);
        acc[m][np] = __builtin_amdgcn_mfma_f32_16x16x32_bf16(bl, xf[np][ks], acc[m][np], 0, 0, 0);
      }
    }

  float b2v = b2[0];
#pragma unroll
  for (int np = 0; np < 2; ++np) {
    float p = 0.f;
#pragma unroll
    for (int m = 0; m < 4; ++m)
#pragma unroll
      for (int r = 0; r < 4; ++r)
        p += sigmoidf_(acc[m][np][r] + sb1[16 * m + 4 * lg + r]) * sw2[16 * m + 4 * lg + r];
    p += __shfl_xor(p, 16);
    p += __shfl_xor(p, 32);
    if (lane < 16) {
      long node = nb + 16 * np + lane;
      va[node] = (p + b2v) * ef[node];
    }
  }
}

// ---- per-layer fused aggregate+transform ---------------------------------
// S0[dst] = sum_{type0} x[src], S1[dst] = sum_{type1} x[src], Sva = sum_{type0} va[src]
// xout[dst] = relu([S0|S1] @ [Wc_pad;Wv] + patch(col62+=S0[62], col63+=Sva) + bias)
__global__ __launch_bounds__(256) void k_aggr2(
    const u16* __restrict__ x, const float* __restrict__ va,
    const int* __restrict__ cnt, const int* __restrict__ slots,
    const u16* __restrict__ wsrc,     // WCV frags (32 x 512)
    const float* __restrict__ bias, u16* __restrict__ xout)
{
  __shared__ u16 sW[32 * 512];        // 32 KB
  __shared__ u16 sShi[4][16 * SPAD];  // 17 KB
  __shared__ u16 sSlo[4][16 * SPAD];  // 17 KB
  __shared__ float sSva[4][16];
  __shared__ float sbias[64];
  {
    const uint4* s4 = reinterpret_cast<const uint4*>(wsrc);
    uint4* d4 = reinterpret_cast<uint4*>(sW);
    for (int i = threadIdx.x; i < 2048; i += 256) d4[i] = s4[i];
  }
  if (threadIdx.x < 64) sbias[threadIdx.x] = bias[threadIdx.x];
  __syncthreads();

  int wid = threadIdx.x >> 6, lane = threadIdx.x & 63;
  int q = lane >> 4, p = lane & 15;
  int nb = (blockIdx.x * 4 + wid) * 16;   // 16 nodes per wave
  if (nb >= NNODE) return;

  // ---- phase 1: gather-sum (quarter q owns node nb+rr*4+q, lane p owns cols 4p..4p+3)
#pragma unroll 1
  for (int rr = 0; rr < 4; ++rr) {
    int node = nb + rr * 4 + q;
    f32x4 a0 = {0.f, 0.f, 0.f, 0.f}, a1 = {0.f, 0.f, 0.f, 0.f};
    float sva = 0.f;
    if (node < NNODE) {
      int deg = cnt[node]; if (deg > SLOTCAP) deg = SLOTCAP;
      const int* sl = slots + (size_t)node * SLOTCAP;
#pragma unroll 1
      for (int j = 0; j < deg; j += 2) {
        int v0 = sl[j];
        bool two = (j + 1 < deg);
        int v1 = two ? sl[j + 1] : 0;
        int s0 = v0 & 0xFFFFF, t0 = (v0 >> 20) & 1;
        int s1 = v1 & 0xFFFFF, t1 = (v1 >> 20) & 1;
        uint2 x0r = *reinterpret_cast<const uint2*>(x + (size_t)s0 * 64 + p * 4);
        float vg0 = va[s0];
        uint2 x1r = make_uint2(0u, 0u);
        float vg1 = 0.f;
        if (two) {
          x1r = *reinterpret_cast<const uint2*>(x + (size_t)s1 * 64 + p * 4);
          vg1 = va[s1];
        }
        float f0 = cvlo(x0r.x), f1 = cvhi(x0r.x), f2 = cvlo(x0r.y), f3 = cvhi(x0r.y);
        if (t0 == 0) { a0[0]+=f0; a0[1]+=f1; a0[2]+=f2; a0[3]+=f3; sva += vg0; }
        else         { a1[0]+=f0; a1[1]+=f1; a1[2]+=f2; a1[3]+=f3; }
        float g0 = cvlo(x1r.x), g1 = cvhi(x1r.x), g2 = cvlo(x1r.y), g3 = cvhi(x1r.y);
        if (t1 == 0) { a0[0]+=g0; a0[1]+=g1; a0[2]+=g2; a0[3]+=g3; sva += (two ? vg1 : 0.f); }
        else         { a1[0]+=g0; a1[1]+=g1; a1[2]+=g2; a1[3]+=g3; }
      }
    }
    int ln = rr * 4 + q;
    u16* Hrow = &sShi[wid][ln * SPAD];
    u16* Lrow = &sSlo[wid][ln * SPAD];
    u16 h[4], l_[4];
#pragma unroll
    for (int c = 0; c < 4; ++c) { h[c] = f2bf(a0[c]); l_[c] = f2bf(a0[c] - bf2f(h[c])); }
    *reinterpret_cast<uint2*>(&Hrow[4 * p]) =
        make_uint2((u32)h[0] | ((u32)h[1] << 16), (u32)h[2] | ((u32)h[3] << 16));
    *reinterpret_cast<uint2*>(&Lrow[4 * p]) =
        make_uint2((u32)l_[0] | ((u32)l_[1] << 16), (u32)l_[2] | ((u32)l_[3] << 16));
#pragma unroll
    for (int c = 0; c < 4; ++c) { h[c] = f2bf(a1[c]); l_[c] = f2bf(a1[c] - bf2f(h[c])); }
    *reinterpret_cast<uint2*>(&Hrow[64 + 4 * p]) =
        make_uint2((u32)h[0] | ((u32)h[1] << 16), (u32)h[2] | ((u32)h[3] << 16));
    *reinterpret_cast<uint2*>(&Lrow[64 + 4 * p]) =
        make_uint2((u32)l_[0] | ((u32)l_[1] << 16), (u32)l_[2] | ((u32)l_[3] << 16));
    if (p == 0) sSva[wid][ln] = sva;
  }
  // wave-local LDS RAW across lanes: force the writes to land before the
  // fragment reads below (don't rely on compiler alias analysis).
  asm volatile("s_waitcnt lgkmcnt(0)" ::: "memory");

  // ---- phase 2: transposed MFMA  D^T = W^T @ S^T  (lane p = node) --------
  frag8 sh[4], sl_[4];
#pragma unroll
  for (int ks = 0; ks < 4; ++ks) {
    sh[ks]  = *reinterpret_cast<const frag8*>(&sShi[wid][p * SPAD + ks * 32 + 8 * q]);
    sl_[ks] = *reinterpret_cast<const frag8*>(&sSlo[wid][p * SPAD + ks * 32 + 8 * q]);
  }
  const f32x4 z = {0.f, 0.f, 0.f, 0.f};
  f32x4 acc[4];
#pragma unroll
  for (int m = 0; m < 4; ++m) acc[m] = z;
#pragma unroll
  for (int ks = 0; ks < 4; ++ks)
#pragma unroll
    for (int m = 0; m < 4; ++m) {
      frag8 wh = *reinterpret_cast<const frag8*>(&sW[((ks * 4 + m) * 512) + lane * 8]);
      frag8 wl = *reinterpret_cast<const frag8*>(&sW[(((16 + ks * 4) + m) * 512) + lane * 8]);
      acc[m] = __builtin_amdgcn_mfma_f32_16x16x32_bf16(wh, sh[ks],  acc[m], 0, 0, 0);
      acc[m] = __builtin_amdgcn_mfma_f32_16x16x32_bf16(wh, sl_[ks], acc[m], 0, 0, 0);
      acc[m] = __builtin_amdgcn_mfma_f32_16x16x32_bf16(wl, sh[ks],  acc[m], 0, 0, 0);
    }

  int node = nb + p;
  if (node >= NNODE) return;
  float s62 = 0.f, svav = 0.f;
  if (q == 3) {
    s62 = bf2f(sShi[wid][p * SPAD + 62]) + bf2f(sSlo[wid][p * SPAD + 62]);
    svav = sSva[wid][p];
  }
  u16* orow = xout + (size_t)node * 64;
#pragma unroll
  for (int m = 0; m < 4; ++m) {
    float o[4];
#pragma unroll
    for (int r = 0; r < 4; ++r) o[r] = acc[m][r] + sbias[16 * m + 4 * q + r];
    // cols 62/63: (S1@Wv) part is already in acc — patch is ADDITIVE.
    if (m == 3 && q == 3) { o[2] += s62; o[3] += svav; }
    u32 p0 = (u32)f2bf(fmaxf(o[0], 0.f)) | ((u32)f2bf(fmaxf(o[1], 0.f)) << 16);
    u32 p1 = (u32)f2bf(fmaxf(o[2], 0.f)) | ((u32)f2bf(fmaxf(o[3], 0.f)) << 16);
    *reinterpret_cast<uint2*>(orow + 16 * m + 4 * q) = make_uint2(p0, p1);
  }
}

// ---- head fc1: [NVAR,320]@[320,64] transposed MFMA, 2 LDS phases ---------
__global__ __launch_bounds__(256) void k_head1(
    const u16* __restrict__ xs, const int* __restrict__ assoc,
    const u16* __restrict__ wp, const float* __restrict__ fb,
    u16* __restrict__ ohi, u16* __restrict__ olo)
{
  __shared__ u16 sB[40 * 512];
  __shared__ float sfb[64];
  if (threadIdx.x < 64) sfb[threadIdx.x] = fb[threadIdx.x];

  int wid = threadIdx.x >> 6, lane = threadIdx.x & 63;
  long ib = ((long)blockIdx.x * 4 + wid) * 32;
  bool act = (ib < NVAR);
  int l15 = lane & 15, lg = lane >> 4;
  long node0 = 0, node1 = 0;
  if (act) { node0 = assoc[ib + l15]; node1 = assoc[ib + 16 + l15]; }

  const f32x4 z = {0.f, 0.f, 0.f, 0.f};
  f32x4 acc[4][2];
#pragma unroll
  for (int m = 0; m < 4; ++m)
#pragma unroll
    for (int np = 0; np < 2; ++np) acc[m][np] = z;

#pragma unroll 1
  for (int ph = 0; ph < 2; ++ph) {
    __syncthreads();
    {
      const uint4* s4 = reinterpret_cast<const uint4*>(wp + WP_FC1(ph));
      uint4* d4 = reinterpret_cast<uint4*>(sB);
      for (int i = threadIdx.x; i < 2560; i += 256) d4[i] = s4[i];
    }
    __syncthreads();
    if (!act) continue;
#pragma unroll
    for (int ks = 0; ks < 5; ++ks) {
      int kg = ph * 160 + ks * 32;
      int pl = kg >> 6, c = (kg & 63) + 8 * lg;
      frag8 a0 = *reinterpret_cast<const frag8*>(xs + ((size_t)pl * NNODE + node0) * 64 + c);
      frag8 a1 = *reinterpret_cast<const frag8*>(xs + ((size_t)pl * NNODE + node1) * 64 + c);
#pragma unroll
      for (int m = 0; m < 4; ++m) {
        frag8 bh = *reinterpret_cast<const frag8*>(&sB[((ks * 4 + m) * 512) + lane * 8]);
        frag8 bl = *reinterpret_cast<const frag8*>(&sB[(((5 + ks) * 4 + m) * 512) + lane * 8]);
        acc[m][0] = __builtin_amdgcn_mfma_f32_16x16x32_bf16(bh, a0, acc[m][0], 0, 0, 0);
        acc[m][0] = __builtin_amdgcn_mfma_f32_16x16x32_bf16(bl, a0, acc[m][0], 0, 0, 0);
        acc[m][1] = __builtin_amdgcn_mfma_f32_16x16x32_bf16(bh, a1, acc[m][1], 0, 0, 0);
        acc[m][1] = __builtin_amdgcn_mfma_f32_16x16x32_bf16(bl, a1, acc[m][1], 0, 0, 0);
      }
    }
  }
  if (!act) return;
#pragma unroll
  for (int np = 0; np < 2; ++np) {
    size_t row = (size_t)(ib + 16 * np + l15) * 64;
#pragma unroll
    for (int m = 0; m < 4; ++m) {
      u16 hi[4], lo[4];
#pragma unroll
      for (int r = 0; r < 4; ++r) {
        float v = fmaxf(acc[m][np][r] + sfb[16 * m + 4 * lg + r], 0.f);
        hi[r] = f2bf(v);
        lo[r] = f2bf(v - bf2f(hi[r]));
      }
      size_t o = row + 16 * m + 4 * lg;
      *reinterpret_cast<uint2*>(ohi + o) =
          make_uint2((u32)hi[0] | ((u32)hi[1] << 16), (u32)hi[2] | ((u32)hi[3] << 16));
      *reinterpret_cast<uint2*>(olo + o) =
          make_uint2((u32)lo[0] | ((u32)lo[1] << 16), (u32)lo[2] | ((u32)lo[3] << 16));
    }
  }
}

// ---- head fc2/fc3: relu([NVAR,64]@[64,64]+b), transposed MFMA ------------
__global__ __launch_bounds__(256) void k_dense64(
    const u16* __restrict__ ahi, const u16* __restrict__ alo,
    const u16* __restrict__ wsrc, const float* __restrict__ b,
    u16* __restrict__ ohi, u16* __restrict__ olo)
{
  __shared__ u16 sB[16 * 512];
  __shared__ float sbv[64];
  {
    const uint4* s4 = reinterpret_cast<const uint4*>(wsrc);
    uint4* d4 = reinterpret_cast<uint4*>(sB);
    for (int i = threadIdx.x; i < 1024; i += 256) d4[i] = s4[i];
  }
  if (threadIdx.x < 64) sbv[threadIdx.x] = b[threadIdx.x];
  __syncthreads();

  int wid = threadIdx.x >> 6, lane = threadIdx.x & 63;
  long ib = ((long)blockIdx.x * 4 + wid) * 32;
  if (ib >= NVAR) return;
  int l15 = lane & 15, lg = lane >> 4;

  frag8 xh[2][2], xl[2][2];
#pragma unroll
  for (int np = 0; np < 2; ++np) {
    const u16* bh_ = ahi + (ib + 16 * np + l15) * 64 + 8 * lg;
    const u16* bl_ = alo + (ib + 16 * np + l15) * 64 + 8 * lg;
    xh[np][0] = *reinterpret_cast<const frag8*>(bh_);
    xh[np][1] = *reinterpret_cast<const frag8*>(bh_ + 32);
    xl[np][0] = *reinterpret_cast<const frag8*>(bl_);
    xl[np][1] = *reinterpret_cast<const frag8*>(bl_ + 32);
  }

  const f32x4 z = {0.f, 0.f, 0.f, 0.f};
  f32x4 acc[4][2];
#pragma unroll
  for (int m = 0; m < 4; ++m)
#pragma unroll
    for (int np = 0; np < 2; ++np) acc[m][np] = z;

#pragma unroll
  for (int ks = 0; ks < 2; ++ks)
#pragma unroll
    for (int m = 0; m < 4; ++m) {
      frag8 bh = *reinterpret_cast<const frag8*>(&sB[((ks * 4 + m) * 512) + lane * 8]);
      frag8 bl = *reinterpret_cast<const frag8*>(&sB[(((2 + ks) * 4 + m) * 512) + lane * 8]);
#pragma unroll
      for (int np = 0; np < 2; ++np) {
        acc[m][np] = __builtin_amdgcn_mfma_f32_16x16x32_bf16(bh, xh[np][ks], acc[m][np], 0, 0, 0);
        acc[m][np] = __builtin_amdgcn_mfma_f32_16x16x32_bf16(bh, xl[np][ks], acc[m][np], 0, 0, 0);
        acc[m][np] = __builtin_amdgcn_mfma_f32_16x16x32_bf16(bl, xh[np][ks], acc[m][np], 0, 0, 0);
      }
    }

#pragma unroll
  for (int np = 0; np < 2; ++np) {
    size_t row = (size_t)(ib + 16 * np + l15) * 64;
#pragma unroll
    for (int m = 0; m < 4; ++m) {
      u16 hi[4], lo[4];
#pragma unroll
      for (int r = 0; r < 4; ++r) {
        float v = fmaxf(acc[m][np][r] + sbv[16 * m + 4 * lg + r], 0.f);
        hi[r] = f2bf(v);
        lo[r] = f2bf(v - bf2f(hi[r]));
      }
      size_t o = row + 16 * m + 4 * lg;
      *reinterpret_cast<uint2*>(ohi + o) =
          make_uint2((u32)hi[0] | ((u32)hi[1] << 16), (u32)hi[2] | ((u32)hi[3] << 16));
      *reinterpret_cast<uint2*>(olo + o) =
          make_uint2((u32)lo[0] | ((u32)lo[1] << 16), (u32)lo[2] | ((u32)lo[3] << 16));
    }
  }
}

// ---- head fc4: dot + bias -> out (hi/lo input) ---------------------------
__global__ __launch_bounds__(256) void k_head4(
    const u16* __restrict__ ahi, const u16* __restrict__ alo,
    const float* __restrict__ w, const float* __restrict__ b,
    float* __restrict__ out)
{
  __shared__ float sw[64];
  if (threadIdx.x < 64) sw[threadIdx.x] = w[threadIdx.x];
  __syncthreads();
  int i = blockIdx.x * 256 + threadIdx.x;
  if (i >= NVAR) return;
  float acc = b[0];
  const uint4* hp = reinterpret_cast<const uint4*>(ahi + (size_t)i * 64);
  const uint4* lp = reinterpret_cast<const uint4*>(alo + (size_t)i * 64);
#pragma unroll
  for (int j = 0; j < 8; ++j) {
    uint4 h = hp[j], l = lp[j];
    acc += (cvlo(h.x) + cvlo(l.x)) * sw[8 * j + 0] + (cvhi(h.x) + cvhi(l.x)) * sw[8 * j + 1];
    acc += (cvlo(h.y) + cvlo(l.y)) * sw[8 * j + 2] + (cvhi(h.y) + cvhi(l.y)) * sw[8 * j + 3];
    acc += (cvlo(h.z) + cvlo(l.z)) * sw[8 * j + 4] + (cvhi(h.z) + cvhi(l.z)) * sw[8 * j + 5];
    acc += (cvlo(h.w) + cvlo(l.w)) * sw[8 * j + 6] + (cvhi(h.w) + cvhi(l.w)) * sw[8 * j + 7];
  }
  out[i] = acc;
}

// ---- launch --------------------------------------------------------------
extern "C" void kernel_launch(void* const* d_in, const int* in_sizes, int n_in,
                              void* d_out, int out_size, void* d_ws, size_t ws_size,
                              hipStream_t stream)
{
  (void)in_sizes; (void)n_in; (void)out_size; (void)ws_size;
  const float* var_nf = (const float*)d_in[0];
  const float* con_nf = (const float*)d_in[1];
  const float* edge_f = (const float*)d_in[2];
  const int*   eidx   = (const int*)d_in[3];
  const int*   etyp   = (const int*)d_in[4];
  const int*   avar   = (const int*)d_in[5];
  const int*   acon   = (const int*)d_in[6];
  const float* vw1 = (const float*)d_in[7];
  const float* vb1 = (const float*)d_in[8];
  const float* vw2 = (const float*)d_in[9];
  const float* vb2 = (const float*)d_in[10];
  const float* cw1 = (const float*)d_in[11];
  const float* cb1 = (const float*)d_in[12];
  const float* cw2 = (const float*)d_in[13];
  const float* cb2 = (const float*)d_in[14];
  const float* hw1 = (const float*)d_in[15];
  const float* hb1 = (const float*)d_in[16];
  const float* hw2 = (const float*)d_in[17];
  const float* hb2 = (const float*)d_in[18];
  const float* wco = (const float*)d_in[19];
  const float* wva = (const float*)d_in[20];
  const float* bia = (const float*)d_in[21];
  const float* f1w = (const float*)d_in[22];
  const float* f1b = (const float*)d_in[23];
  const float* f2w = (const float*)d_in[24];
  const float* f2b = (const float*)d_in[25];
  const float* f3w = (const float*)d_in[26];
  const float* f3b = (const float*)d_in[27];
  const float* f4w = (const float*)d_in[28];
  const float* f4b = (const float*)d_in[29];

  char* ws = (char*)d_ws;
  // xs [0,64M) | cnt [64M,+0.4M) | slots [64.4M,+12.8M) | va [77.2M,+0.56M)
  // | wp [77.76M,+0.35M) | head planes [78.4M ..)
  u16*   xs    = (u16*)ws;
  int*   cnt   = (int*)(ws + 64000000);
  int*   slots = (int*)(ws + 64400000);
  float* va    = (float*)(ws + 77200000);
  u16*   wp    = (u16*)(ws + 77760000);
  u16* hAhi = (u16*)(ws + 78400000);
  u16* hAlo = (u16*)(ws + 86080000);
  u16* hBhi = (u16*)(ws + 93760000);
  u16* hBlo = (u16*)(ws + 101440000);

  const int* esrc = eidx;
  const int* edst = eidx + NEDGE;

  k_prep<<<PREP_TOTAL / 256, 256, 0, stream>>>(hw1, wco, wva, vw2, cw2, f1w, f2w, f3w, wp);
  k_init<<<VAR_BLOCKS + CON_BLOCKS, 256, 0, stream>>>(
      var_nf, con_nf, avar, acon, vw1, vb1, vb2, cw1, cb1, cb2, wp, xs, cnt);
  k_scatter<<<(NEDGE + 255) / 256, 256, 0, stream>>>(esrc, edst, etyp, cnt, slots);

  for (int l = 0; l < 4; ++l) {
    u16* xin  = xs + (size_t)l * NNODE * 64;
    u16* xout = xs + (size_t)(l + 1) * NNODE * 64;
    k_gate<<<(NNODE + 127) / 128, 256, 0, stream>>>(
        xin, edge_f, wp + WP_NODE(l), hb1 + l * 64, hw2 + l * 64, hb2 + l, va);
    k_aggr2<<<(NNODE + 63) / 64, 256, 0, stream>>>(
        xin, va, cnt, slots, wp + WP_NODE(l) + 16 * 512, bia + l * 64, xout);
  }

  k_head1<<<(NVAR + 127) / 128, 256, 0, stream>>>(xs, avar, wp, f1b, hAhi, hAlo);
  k_dense64<<<(NVAR + 127) / 128, 256, 0, stream>>>(hAhi, hAlo, wp + WP_FC2, f2b, hBhi, hBlo);
  k_dense64<<<(NVAR + 127) / 128, 256, 0, stream>>>(hBhi, hBlo, wp + WP_FC3, f3b, hAhi, hAlo);
  k_head4<<<(NVAR + 255) / 256, 256, 0, stream>>>(hAhi, hAlo, f4w, f4b, (float*)d_out);
}

// Round 9
// 337.353 us; speedup vs baseline: 1.4852x; 1.4852x over previous
//
#include <hip/hip_runtime.h>
#include <hip/hip_bf16.h>

typedef unsigned int u32;
typedef unsigned short u16;
typedef __attribute__((ext_vector_type(8))) short frag8;   // 8 bf16 (4 VGPRs)
typedef __attribute__((ext_vector_type(4))) float f32x4;   // MFMA C/D

#define NNODE 100000
#define NVAR  60000
#define NCON  40000
#define NEDGE 500000
#define SLOTCAP 32
#define VAR_BLOCKS 469   // ceil(60000/128)
#define CON_BLOCKS 313   // ceil(40000/128)

// prep-region offsets (u16 units) within wp
// per-layer node image: W1 hi/lo frags 0..15, WCV(128x64 = [Wc_pad;Wv]) hi/lo frags 16..47
#define WP_NODE(l)  ((l) * 24576)
#define WP_VARW2    98304
#define WP_CONW2    106496
#define WP_FC1(ph)  (114688 + (ph) * 20480)
#define WP_FC2      155648
#define WP_FC3      163840
#define PREP_TOTAL  86016

// ---- helpers -------------------------------------------------------------
__device__ __forceinline__ u16 f2bf(float f) {
  u32 u = __float_as_uint(f);
  u32 r = (u + 0x7fffu + ((u >> 16) & 1u)) >> 16;   // RNE
  return (u16)r;
}
__device__ __forceinline__ float bf2f(u16 u) { return __uint_as_float(((u32)u) << 16); }
__device__ __forceinline__ float cvlo(u32 p) { return __uint_as_float(p << 16); }
__device__ __forceinline__ float cvhi(u32 p) { return __uint_as_float(p & 0xffff0000u); }
__device__ __forceinline__ float sigmoidf_(float x) {
  return __builtin_amdgcn_rcpf(1.0f + __expf(-x));
}

// ---- k_prep: format all weight matrices into hi/lo MFMA fragment images --
// frag image layout: frag*512 + lane*8 + j  (lane = (n&15)|(((k&31)>>3)<<4), j=k&7)
__global__ __launch_bounds__(256) void k_prep(
    const float* __restrict__ hw1, const float* __restrict__ wco,
    const float* __restrict__ wva, const float* __restrict__ vw2,
    const float* __restrict__ cw2, const float* __restrict__ f1w,
    const float* __restrict__ f2w, const float* __restrict__ f3w,
    u16* __restrict__ wp)
{
  int g = blockIdx.x * 256 + threadIdx.x;
  if (g >= PREP_TOTAL) return;
  float w; u16* base; int k, n, fr_hi, fr_lo;
  if (g < 49152) {                               // per-layer: W1 (4096) + WCV (8192)
    int l = g / 12288, e = g % 12288;
    base = wp + WP_NODE(l);
    if (e < 4096) {                              // W1 (64x64)
      k = e >> 6; n = e & 63;
      w = hw1[l * 4096 + e];
      int ksp = k >> 5, nt = n >> 4;
      fr_hi = ksp * 4 + nt;                      // 0..7
      fr_lo = (2 + ksp) * 4 + nt;                // 8..15
    } else {                                     // WCV (128x64): rows 0..63 Wc_pad, 64..127 Wv
      int e2 = e - 4096;
      int kk = e2 >> 6; n = e2 & 63;
      if (kk < 64) w = (kk < 62 && n < 62) ? wco[l * 3844 + kk * 62 + n] : 0.f;
      else         w = wva[l * 4096 + (kk - 64) * 64 + n];
      k = kk;
      int kkp = kk >> 5, nt = n >> 4;
      fr_hi = 16 + kkp * 4 + nt;                 // 16..31
      fr_lo = 16 + (4 + kkp) * 4 + nt;           // 32..47
    }
  } else if (g < 53248) {                        // var w2 (62x62 padded)
    int idx = g - 49152; k = idx >> 6; n = idx & 63;
    w = (k < 62 && n < 62) ? vw2[k * 62 + n] : 0.f;
    base = wp + WP_VARW2;
    int ksp = k >> 5, nt = n >> 4;
    fr_hi = ksp * 4 + nt; fr_lo = (2 + ksp) * 4 + nt;
  } else if (g < 57344) {                        // con w2 (63x63 padded)
    int idx = g - 53248; k = idx >> 6; n = idx & 63;
    w = (k < 63 && n < 63) ? cw2[k * 63 + n] : 0.f;
    base = wp + WP_CONW2;
    int ksp = k >> 5, nt = n >> 4;
    fr_hi = ksp * 4 + nt; fr_lo = (2 + ksp) * 4 + nt;
  } else if (g < 77824) {                        // fc1 (320x64), 2 phases
    int e = g - 57344; int kk = e >> 6; n = e & 63;
    int ph = (kk >= 160); k = kk - ph * 160;
    w = f1w[(size_t)kk * 64 + n];
    base = wp + WP_FC1(ph);
    int ksp = k >> 5, nt = n >> 4;
    fr_hi = ksp * 4 + nt; fr_lo = (5 + ksp) * 4 + nt;
  } else if (g < 81920) {                        // fc2 (64x64)
    int idx = g - 77824; k = idx >> 6; n = idx & 63;
    w = f2w[idx];
    base = wp + WP_FC2;
    int ksp = k >> 5, nt = n >> 4;
    fr_hi = ksp * 4 + nt; fr_lo = (2 + ksp) * 4 + nt;
  } else {                                       // fc3 (64x64)
    int idx = g - 81920; k = idx >> 6; n = idx & 63;
    w = f3w[idx];
    base = wp + WP_FC3;
    int ksp = k >> 5, nt = n >> 4;
    fr_hi = ksp * 4 + nt; fr_lo = (2 + ksp) * 4 + nt;
  }
  u16 hi = f2bf(w);
  u16 lo = f2bf(w - bf2f(hi));
  int lane = (n & 15) | (((k & 31) >> 3) << 4);
  int j = k & 7;
  base[fr_hi * 512 + lane * 8 + j] = hi;
  base[fr_lo * 512 + lane * 8 + j] = lo;
}

// ---- fused var+con init (MFMA, transposed) + cnt zeroing -----------------
__global__ __launch_bounds__(256) void k_init(
    const float* __restrict__ vf, const float* __restrict__ cf,
    const int* __restrict__ avar, const int* __restrict__ acon,
    const float* __restrict__ vw1, const float* __restrict__ vb1, const float* __restrict__ vb2,
    const float* __restrict__ cw1, const float* __restrict__ cb1, const float* __restrict__ cb2,
    const u16* __restrict__ wp, u16* __restrict__ x0, int* __restrict__ cnt)
{
  for (int i = blockIdx.x * 256 + threadIdx.x; i < NNODE; i += gridDim.x * 256) cnt[i] = 0;

  const bool isVar = blockIdx.x < VAR_BLOCKS;
  const int bbase = isVar ? blockIdx.x : (blockIdx.x - VAR_BLOCKS);
  const int nItems = isVar ? NVAR : NCON;
  const int KD = isVar ? 62 : 63;
  const float* in  = isVar ? vf : cf;
  const int*   asc = isVar ? avar : acon;
  const float* w1  = isVar ? vw1 : cw1;
  const float* b1  = isVar ? vb1 : cb1;
  const float* b2  = isVar ? vb2 : cb2;
  const u16*   src = wp + (isVar ? WP_VARW2 : WP_CONW2);

  __shared__ u16 sB[16 * 512];
  __shared__ float sw1[64], sb1[64], sb2[64];
  {
    const uint4* s4 = reinterpret_cast<const uint4*>(src);
    uint4* d4 = reinterpret_cast<uint4*>(sB);
    for (int i = threadIdx.x; i < 1024; i += 256) d4[i] = s4[i];
  }
  if (threadIdx.x < 64) {
    int t = threadIdx.x;
    sw1[t] = (t < KD) ? w1[t] : 0.f;
    sb1[t] = (t < KD) ? b1[t] : 0.f;
    sb2[t] = (t < KD) ? b2[t] : 0.f;
  }
  __syncthreads();

  int wid = threadIdx.x >> 6, lane = threadIdx.x & 63;
  long ib = ((long)bbase * 4 + wid) * 32;
  if (ib >= nItems) return;
  int l15 = lane & 15, lg = lane >> 4;

  float w1r[16], b1r[16];
#pragma unroll
  for (int ks = 0; ks < 2; ++ks)
#pragma unroll
    for (int j = 0; j < 8; ++j) {
      int k = 32 * ks + 8 * lg + j;
      w1r[ks * 8 + j] = sw1[k]; b1r[ks * 8 + j] = sb1[k];
    }

  float v0 = in[ib + l15], v1 = in[ib + 16 + l15];
  frag8 hh[2][2], hl[2][2];
#pragma unroll
  for (int np = 0; np < 2; ++np) {
    float v = np ? v1 : v0;
#pragma unroll
    for (int ks = 0; ks < 2; ++ks) {
      frag8 th, tl;
#pragma unroll
      for (int j = 0; j < 8; ++j) {
        float h = fmaxf(fmaf(v, w1r[ks * 8 + j], b1r[ks * 8 + j]), 0.f);
        u16 hi = f2bf(h);
        u16 lo = f2bf(h - bf2f(hi));
        th[j] = (short)hi; tl[j] = (short)lo;
      }
      hh[np][ks] = th; hl[np][ks] = tl;
    }
  }

  const f32x4 z = {0.f, 0.f, 0.f, 0.f};
  f32x4 acc[4][2];
#pragma unroll
  for (int m = 0; m < 4; ++m)
#pragma unroll
    for (int np = 0; np < 2; ++np) acc[m][np] = z;

#pragma unroll
  for (int ks = 0; ks < 2; ++ks)
#pragma unroll
    for (int m = 0; m < 4; ++m) {
      frag8 bh = *reinterpret_cast<const frag8*>(&sB[((ks * 4 + m) * 512) + lane * 8]);
      frag8 bl = *reinterpret_cast<const frag8*>(&sB[(((2 + ks) * 4 + m) * 512) + lane * 8]);
#pragma unroll
      for (int np = 0; np < 2; ++np) {
        acc[m][np] = __builtin_amdgcn_mfma_f32_16x16x32_bf16(bh, hh[np][ks], acc[m][np], 0, 0, 0);
        acc[m][np] = __builtin_amdgcn_mfma_f32_16x16x32_bf16(bh, hl[np][ks], acc[m][np], 0, 0, 0);
        acc[m][np] = __builtin_amdgcn_mfma_f32_16x16x32_bf16(bl, hh[np][ks], acc[m][np], 0, 0, 0);
      }
    }

#pragma unroll
  for (int np = 0; np < 2; ++np) {
    long r = asc[ib + 16 * np + l15];
    float vv = np ? v1 : v0;
    u16* orow = x0 + r * 64;
#pragma unroll
    for (int m = 0; m < 4; ++m) {
      float o[4];
#pragma unroll
      for (int rr = 0; rr < 4; ++rr) o[rr] = acc[m][np][rr] + sb2[16 * m + 4 * lg + rr];
      if (m == 3 && lg == 3) {
        if (isVar) { o[2] = vv; o[3] = 1.0f; } else { o[3] = vv; }
      }
      u32 p0 = (u32)f2bf(o[0]) | ((u32)f2bf(o[1]) << 16);
      u32 p1 = (u32)f2bf(o[2]) | ((u32)f2bf(o[3]) << 16);
      *reinterpret_cast<uint2*>(orow + 16 * m + 4 * lg) = make_uint2(p0, p1);
    }
  }
}

// ---- CSR-ish bucket build: slots[d][pos] = src | (type<<20) --------------
__global__ __launch_bounds__(256) void k_scatter(
    const int* __restrict__ src, const int* __restrict__ dst,
    const int* __restrict__ et, int* __restrict__ cnt, int* __restrict__ slots)
{
  int e = blockIdx.x * 256 + threadIdx.x;
  if (e >= NEDGE) return;
  int d = dst[e];
  int pos = atomicAdd(&cnt[d], 1);
  if (pos < SLOTCAP) slots[d * SLOTCAP + pos] = src[e] | ((et[e] & 1) << 20);
}

// ---- per-layer gate: va[n] = (sigmoid(x@W1+b1).w2+b2)*ef[n] --------------
__global__ __launch_bounds__(256) void k_gate(
    const u16* __restrict__ x, const float* __restrict__ ef,
    const u16* __restrict__ wsrc,     // W1 frags (0..15)
    const float* __restrict__ b1, const float* __restrict__ w2,
    const float* __restrict__ b2, float* __restrict__ va)
{
  __shared__ u16 sB[16 * 512];
  __shared__ float sb1[64], sw2[64];
  {
    const uint4* s4 = reinterpret_cast<const uint4*>(wsrc);
    uint4* d4 = reinterpret_cast<uint4*>(sB);
    for (int i = threadIdx.x; i < 1024; i += 256) d4[i] = s4[i];
  }
  if (threadIdx.x < 64) { sb1[threadIdx.x] = b1[threadIdx.x]; sw2[threadIdx.x] = w2[threadIdx.x]; }
  __syncthreads();

  int wid = threadIdx.x >> 6, lane = threadIdx.x & 63;
  long nb = ((long)blockIdx.x * 4 + wid) * 32;
  if (nb >= NNODE) return;
  int l15 = lane & 15, lg = lane >> 4;

  frag8 xf[2][2];
#pragma unroll
  for (int np = 0; np < 2; ++np) {
    const u16* base = x + (nb + 16 * np + l15) * 64 + 8 * lg;
    xf[np][0] = *reinterpret_cast<const frag8*>(base);
    xf[np][1] = *reinterpret_cast<const frag8*>(base + 32);
  }

  const f32x4 z = {0.f, 0.f, 0.f, 0.f};
  f32x4 acc[4][2];
#pragma unroll
  for (int m = 0; m < 4; ++m)
#pragma unroll
    for (int np = 0; np < 2; ++np) acc[m][np] = z;

#pragma unroll
  for (int ks = 0; ks < 2; ++ks)
#pragma unroll
    for (int m = 0; m < 4; ++m) {
      frag8 bh = *reinterpret_cast<const frag8*>(&sB[((ks * 4 + m) * 512) + lane * 8]);
      frag8 bl = *reinterpret_cast<const frag8*>(&sB[(((2 + ks) * 4 + m) * 512) + lane * 8]);
#pragma unroll
      for (int np = 0; np < 2; ++np) {
        acc[m][np] = __builtin_amdgcn_mfma_f32_16x16x32_bf16(bh, xf[np][ks], acc[m][np], 0, 0, 0);
        acc[m][np] = __builtin_amdgcn_mfma_f32_16x16x32_bf16(bl, xf[np][ks], acc[m][np], 0, 0, 0);
      }
    }

  float b2v = b2[0];
#pragma unroll
  for (int np = 0; np < 2; ++np) {
    float p = 0.f;
#pragma unroll
    for (int m = 0; m < 4; ++m)
#pragma unroll
      for (int r = 0; r < 4; ++r)
        p += sigmoidf_(acc[m][np][r] + sb1[16 * m + 4 * lg + r]) * sw2[16 * m + 4 * lg + r];
    p += __shfl_xor(p, 16);
    p += __shfl_xor(p, 32);
    if (lane < 16) {
      long node = nb + 16 * np + lane;
      va[node] = (p + b2v) * ef[node];
    }
  }
}

// ---- per-layer fused aggregate+transform (LDS-free, lane=(node,kchunk)) --
// Lane (p,q): node = nb+p, owns features {ks*32+8q..+7} of S0 (ks=0,1) and S1.
// Accumulate straight into MFMA B-fragment register layout; no LDS transpose.
// xout[dst] = relu([S0|S1]@[Wc_pad;Wv] + add-patch(col62+=S0[62], col63+=Sva) + b)
__global__ __launch_bounds__(256) void k_aggr2(
    const u16* __restrict__ x, const float* __restrict__ va,
    const int* __restrict__ cnt, const int* __restrict__ slots,
    const u16* __restrict__ wsrc,     // WCV frags (32 x 512): hi 0..15, lo 16..31
    const float* __restrict__ bias, u16* __restrict__ xout)
{
  int wid = threadIdx.x >> 6, lane = threadIdx.x & 63;
  int q = lane >> 4, p = lane & 15;
  int nb = (blockIdx.x * 4 + wid) * 16;
  int node = nb + p;
  bool active = (node < NNODE);

  // a0 = S0 features [ks*8+j] (k = ks*32+8q+j), a1 = S1 same; f32 exact.
  float a0[16], a1[16];
#pragma unroll
  for (int i = 0; i < 16; ++i) { a0[i] = 0.f; a1[i] = 0.f; }
  float sva = 0.f;

  if (active) {
    int deg = cnt[node]; if (deg > SLOTCAP) deg = SLOTCAP;
    const int* sl = slots + (size_t)node * SLOTCAP;
#pragma unroll 1
    for (int j0 = 0; j0 < deg; j0 += 4) {
      int4 sv = *reinterpret_cast<const int4*>(sl + j0);   // 16B-aligned
#pragma unroll
      for (int k = 0; k < 4; ++k) {
        int v = (k == 0) ? sv.x : (k == 1) ? sv.y : (k == 2) ? sv.z : sv.w;
        bool ok = (j0 + k < deg);
        int s = ok ? (v & 0xFFFFF) : 0;
        int t = (v >> 20) & 1;
        const u16* xr = x + (size_t)s * 64 + 8 * q;
        uint4 r0 = *reinterpret_cast<const uint4*>(xr);        // feats 8q..8q+7
        uint4 r1 = *reinterpret_cast<const uint4*>(xr + 32);   // feats 32+8q..+7
        float vg = va[s];
        float m0 = (ok && t == 0) ? 1.f : 0.f;
        float m1 = (ok && t != 0) ? 1.f : 0.f;
        float f[16] = {cvlo(r0.x), cvhi(r0.x), cvlo(r0.y), cvhi(r0.y),
                       cvlo(r0.z), cvhi(r0.z), cvlo(r0.w), cvhi(r0.w),
                       cvlo(r1.x), cvhi(r1.x), cvlo(r1.y), cvhi(r1.y),
                       cvlo(r1.z), cvhi(r1.z), cvlo(r1.w), cvhi(r1.w)};
#pragma unroll
        for (int i = 0; i < 16; ++i) {
          a0[i] = fmaf(f[i], m0, a0[i]);
          a1[i] = fmaf(f[i], m1, a1[i]);
        }
        sva = fmaf(vg, m0, sva);
      }
    }
  }

  // exact-f32 patch values (feature 62 = ks=1, q=3, j=6 -> a0[14] on lane q==3)
  float s62 = a0[14];

  // in-register hi/lo split into B-fragments
  frag8 sh[4], sl_[4];
#pragma unroll
  for (int ks = 0; ks < 2; ++ks)
#pragma unroll
    for (int j = 0; j < 8; ++j) {
      float v0 = a0[ks * 8 + j];
      u16 h0 = f2bf(v0);
      sh[ks][j] = (short)h0; sl_[ks][j] = (short)f2bf(v0 - bf2f(h0));
      float v1 = a1[ks * 8 + j];
      u16 h1 = f2bf(v1);
      sh[2 + ks][j] = (short)h1; sl_[2 + ks][j] = (short)f2bf(v1 - bf2f(h1));
    }

  // MFMA: D^T = W^T @ S^T ; W frags direct from global (uniform -> L2 bcast)
  const f32x4 z = {0.f, 0.f, 0.f, 0.f};
  f32x4 acc[4];
#pragma unroll
  for (int m = 0; m < 4; ++m) acc[m] = z;
#pragma unroll
  for (int ks = 0; ks < 4; ++ks)
#pragma unroll
    for (int m = 0; m < 4; ++m) {
      frag8 wh = *reinterpret_cast<const frag8*>(&wsrc[((ks * 4 + m) * 512) + lane * 8]);
      frag8 wl = *reinterpret_cast<const frag8*>(&wsrc[((16 + ks * 4 + m) * 512) + lane * 8]);
      acc[m] = __builtin_amdgcn_mfma_f32_16x16x32_bf16(wh, sh[ks],  acc[m], 0, 0, 0);
      acc[m] = __builtin_amdgcn_mfma_f32_16x16x32_bf16(wh, sl_[ks], acc[m], 0, 0, 0);
      acc[m] = __builtin_amdgcn_mfma_f32_16x16x32_bf16(wl, sh[ks],  acc[m], 0, 0, 0);
    }

  if (!active) return;
  u16* orow = xout + (size_t)node * 64;
#pragma unroll
  for (int m = 0; m < 4; ++m) {
    f32x4 bv = *reinterpret_cast<const f32x4*>(bias + 16 * m + 4 * q);
    float o[4];
#pragma unroll
    for (int r = 0; r < 4; ++r) o[r] = acc[m][r] + bv[r];
    // cols 62/63: (S1@Wv) already in acc — patch is ADDITIVE (exact f32).
    if (m == 3 && q == 3) { o[2] += s62; o[3] += sva; }
    u32 p0 = (u32)f2bf(fmaxf(o[0], 0.f)) | ((u32)f2bf(fmaxf(o[1], 0.f)) << 16);
    u32 p1 = (u32)f2bf(fmaxf(o[2], 0.f)) | ((u32)f2bf(fmaxf(o[3], 0.f)) << 16);
    *reinterpret_cast<uint2*>(orow + 16 * m + 4 * q) = make_uint2(p0, p1);
  }
}

// ---- head fc1: [NVAR,320]@[320,64] transposed MFMA, 2 LDS phases ---------
__global__ __launch_bounds__(256) void k_head1(
    const u16* __restrict__ xs, const int* __restrict__ assoc,
    const u16* __restrict__ wp, const float* __restrict__ fb,
    u16* __restrict__ ohi, u16* __restrict__ olo)
{
  __shared__ u16 sB[40 * 512];
  __shared__ float sfb[64];
  if (threadIdx.x < 64) sfb[threadIdx.x] = fb[threadIdx.x];

  int wid = threadIdx.x >> 6, lane = threadIdx.x & 63;
  long ib = ((long)blockIdx.x * 4 + wid) * 32;
  bool act = (ib < NVAR);
  int l15 = lane & 15, lg = lane >> 4;
  long node0 = 0, node1 = 0;
  if (act) { node0 = assoc[ib + l15]; node1 = assoc[ib + 16 + l15]; }

  const f32x4 z = {0.f, 0.f, 0.f, 0.f};
  f32x4 acc[4][2];
#pragma unroll
  for (int m = 0; m < 4; ++m)
#pragma unroll
    for (int np = 0; np < 2; ++np) acc[m][np] = z;

#pragma unroll 1
  for (int ph = 0; ph < 2; ++ph) {
    __syncthreads();
    {
      const uint4* s4 = reinterpret_cast<const uint4*>(wp + WP_FC1(ph));
      uint4* d4 = reinterpret_cast<uint4*>(sB);
      for (int i = threadIdx.x; i < 2560; i += 256) d4[i] = s4[i];
    }
    __syncthreads();
    if (!act) continue;
#pragma unroll
    for (int ks = 0; ks < 5; ++ks) {
      int kg = ph * 160 + ks * 32;
      int pl = kg >> 6, c = (kg & 63) + 8 * lg;
      frag8 a0 = *reinterpret_cast<const frag8*>(xs + ((size_t)pl * NNODE + node0) * 64 + c);
      frag8 a1 = *reinterpret_cast<const frag8*>(xs + ((size_t)pl * NNODE + node1) * 64 + c);
#pragma unroll
      for (int m = 0; m < 4; ++m) {
        frag8 bh = *reinterpret_cast<const frag8*>(&sB[((ks * 4 + m) * 512) + lane * 8]);
        frag8 bl = *reinterpret_cast<const frag8*>(&sB[(((5 + ks) * 4 + m) * 512) + lane * 8]);
        acc[m][0] = __builtin_amdgcn_mfma_f32_16x16x32_bf16(bh, a0, acc[m][0], 0, 0, 0);
        acc[m][0] = __builtin_amdgcn_mfma_f32_16x16x32_bf16(bl, a0, acc[m][0], 0, 0, 0);
        acc[m][1] = __builtin_amdgcn_mfma_f32_16x16x32_bf16(bh, a1, acc[m][1], 0, 0, 0);
        acc[m][1] = __builtin_amdgcn_mfma_f32_16x16x32_bf16(bl, a1, acc[m][1], 0, 0, 0);
      }
    }
  }
  if (!act) return;
#pragma unroll
  for (int np = 0; np < 2; ++np) {
    size_t row = (size_t)(ib + 16 * np + l15) * 64;
#pragma unroll
    for (int m = 0; m < 4; ++m) {
      u16 hi[4], lo[4];
#pragma unroll
      for (int r = 0; r < 4; ++r) {
        float v = fmaxf(acc[m][np][r] + sfb[16 * m + 4 * lg + r], 0.f);
        hi[r] = f2bf(v);
        lo[r] = f2bf(v - bf2f(hi[r]));
      }
      size_t o = row + 16 * m + 4 * lg;
      *reinterpret_cast<uint2*>(ohi + o) =
          make_uint2((u32)hi[0] | ((u32)hi[1] << 16), (u32)hi[2] | ((u32)hi[3] << 16));
      *reinterpret_cast<uint2*>(olo + o) =
          make_uint2((u32)lo[0] | ((u32)lo[1] << 16), (u32)lo[2] | ((u32)lo[3] << 16));
    }
  }
}

// ---- head fc2/fc3: relu([NVAR,64]@[64,64]+b), transposed MFMA ------------
__global__ __launch_bounds__(256) void k_dense64(
    const u16* __restrict__ ahi, const u16* __restrict__ alo,
    const u16* __restrict__ wsrc, const float* __restrict__ b,
    u16* __restrict__ ohi, u16* __restrict__ olo)
{
  __shared__ u16 sB[16 * 512];
  __shared__ float sbv[64];
  {
    const uint4* s4 = reinterpret_cast<const uint4*>(wsrc);
    uint4* d4 = reinterpret_cast<uint4*>(sB);
    for (int i = threadIdx.x; i < 1024; i += 256) d4[i] = s4[i];
  }
  if (threadIdx.x < 64) sbv[threadIdx.x] = b[threadIdx.x];
  __syncthreads();

  int wid = threadIdx.x >> 6, lane = threadIdx.x & 63;
  long ib = ((long)blockIdx.x * 4 + wid) * 32;
  if (ib >= NVAR) return;
  int l15 = lane & 15, lg = lane >> 4;

  frag8 xh[2][2], xl[2][2];
#pragma unroll
  for (int np = 0; np < 2; ++np) {
    const u16* bh_ = ahi + (ib + 16 * np + l15) * 64 + 8 * lg;
    const u16* bl_ = alo + (ib + 16 * np + l15) * 64 + 8 * lg;
    xh[np][0] = *reinterpret_cast<const frag8*>(bh_);
    xh[np][1] = *reinterpret_cast<const frag8*>(bh_ + 32);
    xl[np][0] = *reinterpret_cast<const frag8*>(bl_);
    xl[np][1] = *reinterpret_cast<const frag8*>(bl_ + 32);
  }

  const f32x4 z = {0.f, 0.f, 0.f, 0.f};
  f32x4 acc[4][2];
#pragma unroll
  for (int m = 0; m < 4; ++m)
#pragma unroll
    for (int np = 0; np < 2; ++np) acc[m][np] = z;

#pragma unroll
  for (int ks = 0; ks < 2; ++ks)
#pragma unroll
    for (int m = 0; m < 4; ++m) {
      frag8 bh = *reinterpret_cast<const frag8*>(&sB[((ks * 4 + m) * 512) + lane * 8]);
      frag8 bl = *reinterpret_cast<const frag8*>(&sB[(((2 + ks) * 4 + m) * 512) + lane * 8]);
#pragma unroll
      for (int np = 0; np < 2; ++np) {
        acc[m][np] = __builtin_amdgcn_mfma_f32_16x16x32_bf16(bh, xh[np][ks], acc[m][np], 0, 0, 0);
        acc[m][np] = __builtin_amdgcn_mfma_f32_16x16x32_bf16(bh, xl[np][ks], acc[m][np], 0, 0, 0);
        acc[m][np] = __builtin_amdgcn_mfma_f32_16x16x32_bf16(bl, xh[np][ks], acc[m][np], 0, 0, 0);
      }
    }

#pragma unroll
  for (int np = 0; np < 2; ++np) {
    size_t row = (size_t)(ib + 16 * np + l15) * 64;
#pragma unroll
    for (int m = 0; m < 4; ++m) {
      u16 hi[4], lo[4];
#pragma unroll
      for (int r = 0; r < 4; ++r) {
        float v = fmaxf(acc[m][np][r] + sbv[16 * m + 4 * lg + r], 0.f);
        hi[r] = f2bf(v);
        lo[r] = f2bf(v - bf2f(hi[r]));
      }
      size_t o = row + 16 * m + 4 * lg;
      *reinterpret_cast<uint2*>(ohi + o) =
          make_uint2((u32)hi[0] | ((u32)hi[1] << 16), (u32)hi[2] | ((u32)hi[3] << 16));
      *reinterpret_cast<uint2*>(olo + o) =
          make_uint2((u32)lo[0] | ((u32)lo[1] << 16), (u32)lo[2] | ((u32)lo[3] << 16));
    }
  }
}

// ---- head fc4: dot + bias -> out (hi/lo input) ---------------------------
__global__ __launch_bounds__(256) void k_head4(
    const u16* __restrict__ ahi, const u16* __restrict__ alo,
    const float* __restrict__ w, const float* __restrict__ b,
    float* __restrict__ out)
{
  __shared__ float sw[64];
  if (threadIdx.x < 64) sw[threadIdx.x] = w[threadIdx.x];
  __syncthreads();
  int i = blockIdx.x * 256 + threadIdx.x;
  if (i >= NVAR) return;
  float acc = b[0];
  const uint4* hp = reinterpret_cast<const uint4*>(ahi + (size_t)i * 64);
  const uint4* lp = reinterpret_cast<const uint4*>(alo + (size_t)i * 64);
#pragma unroll
  for (int j = 0; j < 8; ++j) {
    uint4 h = hp[j], l = lp[j];
    acc += (cvlo(h.x) + cvlo(l.x)) * sw[8 * j + 0] + (cvhi(h.x) + cvhi(l.x)) * sw[8 * j + 1];
    acc += (cvlo(h.y) + cvlo(l.y)) * sw[8 * j + 2] + (cvhi(h.y) + cvhi(l.y)) * sw[8 * j + 3];
    acc += (cvlo(h.z) + cvlo(l.z)) * sw[8 * j + 4] + (cvhi(h.z) + cvhi(l.z)) * sw[8 * j + 5];
    acc += (cvlo(h.w) + cvlo(l.w)) * sw[8 * j + 6] + (cvhi(h.w) + cvhi(l.w)) * sw[8 * j + 7];
  }
  out[i] = acc;
}

// ---- launch --------------------------------------------------------------
extern "C" void kernel_launch(void* const* d_in, const int* in_sizes, int n_in,
                              void* d_out, int out_size, void* d_ws, size_t ws_size,
                              hipStream_t stream)
{
  (void)in_sizes; (void)n_in; (void)out_size; (void)ws_size;
  const float* var_nf = (const float*)d_in[0];
  const float* con_nf = (const float*)d_in[1];
  const float* edge_f = (const float*)d_in[2];
  const int*   eidx   = (const int*)d_in[3];
  const int*   etyp   = (const int*)d_in[4];
  const int*   avar   = (const int*)d_in[5];
  const int*   acon   = (const int*)d_in[6];
  const float* vw1 = (const float*)d_in[7];
  const float* vb1 = (const float*)d_in[8];
  const float* vw2 = (const float*)d_in[9];
  const float* vb2 = (const float*)d_in[10];
  const float* cw1 = (const float*)d_in[11];
  const float* cb1 = (const float*)d_in[12];
  const float* cw2 = (const float*)d_in[13];
  const float* cb2 = (const float*)d_in[14];
  const float* hw1 = (const float*)d_in[15];
  const float* hb1 = (const float*)d_in[16];
  const float* hw2 = (const float*)d_in[17];
  const float* hb2 = (const float*)d_in[18];
  const float* wco = (const float*)d_in[19];
  const float* wva = (const float*)d_in[20];
  const float* bia = (const float*)d_in[21];
  const float* f1w = (const float*)d_in[22];
  const float* f1b = (const float*)d_in[23];
  const float* f2w = (const float*)d_in[24];
  const float* f2b = (const float*)d_in[25];
  const float* f3w = (const float*)d_in[26];
  const float* f3b = (const float*)d_in[27];
  const float* f4w = (const float*)d_in[28];
  const float* f4b = (const float*)d_in[29];

  char* ws = (char*)d_ws;
  // xs [0,64M) | cnt [64M,+0.4M) | slots [64.4M,+12.8M) | va [77.2M,+0.56M)
  // | wp [77.76M,+0.35M) | head planes [78.4M ..)
  u16*   xs    = (u16*)ws;
  int*   cnt   = (int*)(ws + 64000000);
  int*   slots = (int*)(ws + 64400000);
  float* va    = (float*)(ws + 77200000);
  u16*   wp    = (u16*)(ws + 77760000);
  u16* hAhi = (u16*)(ws + 78400000);
  u16* hAlo = (u16*)(ws + 86080000);
  u16* hBhi = (u16*)(ws + 93760000);
  u16* hBlo = (u16*)(ws + 101440000);

  const int* esrc = eidx;
  const int* edst = eidx + NEDGE;

  k_prep<<<PREP_TOTAL / 256, 256, 0, stream>>>(hw1, wco, wva, vw2, cw2, f1w, f2w, f3w, wp);
  k_init<<<VAR_BLOCKS + CON_BLOCKS, 256, 0, stream>>>(
      var_nf, con_nf, avar, acon, vw1, vb1, vb2, cw1, cb1, cb2, wp, xs, cnt);
  k_scatter<<<(NEDGE + 255) / 256, 256, 0, stream>>>(esrc, edst, etyp, cnt, slots);

  for (int l = 0; l < 4; ++l) {
    u16* xin  = xs + (size_t)l * NNODE * 64;
    u16* xout = xs + (size_t)(l + 1) * NNODE * 64;
    k_gate<<<(NNODE + 127) / 128, 256, 0, stream>>>(
        xin, edge_f, wp + WP_NODE(l), hb1 + l * 64, hw2 + l * 64, hb2 + l, va);
    k_aggr2<<<(NNODE + 63) / 64, 256, 0, stream>>>(
        xin, va, cnt, slots, wp + WP_NODE(l) + 16 * 512, bia + l * 64, xout);
  }

  k_head1<<<(NVAR + 127) / 128, 256, 0, stream>>>(xs, avar, wp, f1b, hAhi, hAlo);
  k_dense64<<<(NVAR + 127) / 128, 256, 0, stream>>>(hAhi, hAlo, wp + WP_FC2, f2b, hBhi, hBlo);
  k_dense64<<<(NVAR + 127) / 128, 256, 0, stream>>>(hBhi, hBlo, wp + WP_FC3, f3b, hAhi, hAlo);
  k_head4<<<(NVAR + 255) / 256, 256, 0, stream>>>(hAhi, hAlo, f4w, f4b, (float*)d_out);
}

// Round 12
// 330.629 us; speedup vs baseline: 1.5154x; 1.0203x over previous
//
#include <hip/hip_runtime.h>
#include <hip/hip_bf16.h>

typedef unsigned int u32;
typedef unsigned short u16;
typedef __attribute__((ext_vector_type(8))) short frag8;   // 8 bf16 (4 VGPRs)
typedef __attribute__((ext_vector_type(4))) float f32x4;   // MFMA C/D

#define NNODE 100000
#define NVAR  60000
#define NCON  40000
#define NEDGE 500000
#define SLOTCAP 32
#define VAR_BLOCKS 469   // ceil(60000/128)
#define CON_BLOCKS 313   // ceil(40000/128)
#define XPAD 68          // LDS transpose row stride (u16): 34 dwords -> conflict-light

// prep-region offsets (u16 units) within wp
// per-layer node image: W1 hi/lo frags 0..15, WCV(128x64 = [Wc_pad;Wv]) hi/lo frags 16..47
#define WP_NODE(l)  ((l) * 24576)
#define WP_VARW2    98304
#define WP_CONW2    106496
#define WP_FC1(ph)  (114688 + (ph) * 20480)
#define WP_FC2      155648
#define WP_FC3      163840
#define PREP_TOTAL  86016

// ---- helpers -------------------------------------------------------------
__device__ __forceinline__ u16 f2bf(float f) {
  u32 u = __float_as_uint(f);
  u32 r = (u + 0x7fffu + ((u >> 16) & 1u)) >> 16;   // RNE
  return (u16)r;
}
__device__ __forceinline__ float bf2f(u16 u) { return __uint_as_float(((u32)u) << 16); }
__device__ __forceinline__ float cvlo(u32 p) { return __uint_as_float(p << 16); }
__device__ __forceinline__ float cvhi(u32 p) { return __uint_as_float(p & 0xffff0000u); }
__device__ __forceinline__ float sigmoidf_(float x) {
  return __builtin_amdgcn_rcpf(1.0f + __expf(-x));
}

// ---- k_prep: format all weight matrices into hi/lo MFMA fragment images --
// frag image layout: frag*512 + lane*8 + j  (lane = (n&15)|(((k&31)>>3)<<4), j=k&7)
__global__ __launch_bounds__(256) void k_prep(
    const float* __restrict__ hw1, const float* __restrict__ wco,
    const float* __restrict__ wva, const float* __restrict__ vw2,
    const float* __restrict__ cw2, const float* __restrict__ f1w,
    const float* __restrict__ f2w, const float* __restrict__ f3w,
    u16* __restrict__ wp)
{
  int g = blockIdx.x * 256 + threadIdx.x;
  if (g >= PREP_TOTAL) return;
  float w; u16* base; int k, n, fr_hi, fr_lo;
  if (g < 49152) {                               // per-layer: W1 (4096) + WCV (8192)
    int l = g / 12288, e = g % 12288;
    base = wp + WP_NODE(l);
    if (e < 4096) {                              // W1 (64x64)
      k = e >> 6; n = e & 63;
      w = hw1[l * 4096 + e];
      int ksp = k >> 5, nt = n >> 4;
      fr_hi = ksp * 4 + nt;                      // 0..7
      fr_lo = (2 + ksp) * 4 + nt;                // 8..15
    } else {                                     // WCV (128x64): rows 0..63 Wc_pad, 64..127 Wv
      int e2 = e - 4096;
      int kk = e2 >> 6; n = e2 & 63;
      if (kk < 64) w = (kk < 62 && n < 62) ? wco[l * 3844 + kk * 62 + n] : 0.f;
      else         w = wva[l * 4096 + (kk - 64) * 64 + n];
      k = kk;
      int kkp = kk >> 5, nt = n >> 4;
      fr_hi = 16 + kkp * 4 + nt;                 // 16..31
      fr_lo = 16 + (4 + kkp) * 4 + nt;           // 32..47
    }
  } else if (g < 53248) {                        // var w2 (62x62 padded)
    int idx = g - 49152; k = idx >> 6; n = idx & 63;
    w = (k < 62 && n < 62) ? vw2[k * 62 + n] : 0.f;
    base = wp + WP_VARW2;
    int ksp = k >> 5, nt = n >> 4;
    fr_hi = ksp * 4 + nt; fr_lo = (2 + ksp) * 4 + nt;
  } else if (g < 57344) {                        // con w2 (63x63 padded)
    int idx = g - 53248; k = idx >> 6; n = idx & 63;
    w = (k < 63 && n < 63) ? cw2[k * 63 + n] : 0.f;
    base = wp + WP_CONW2;
    int ksp = k >> 5, nt = n >> 4;
    fr_hi = ksp * 4 + nt; fr_lo = (2 + ksp) * 4 + nt;
  } else if (g < 77824) {                        // fc1 (320x64), 2 phases
    int e = g - 57344; int kk = e >> 6; n = e & 63;
    int ph = (kk >= 160); k = kk - ph * 160;
    w = f1w[(size_t)kk * 64 + n];
    base = wp + WP_FC1(ph);
    int ksp = k >> 5, nt = n >> 4;
    fr_hi = ksp * 4 + nt; fr_lo = (5 + ksp) * 4 + nt;
  } else if (g < 81920) {                        // fc2 (64x64)
    int idx = g - 77824; k = idx >> 6; n = idx & 63;
    w = f2w[idx];
    base = wp + WP_FC2;
    int ksp = k >> 5, nt = n >> 4;
    fr_hi = ksp * 4 + nt; fr_lo = (2 + ksp) * 4 + nt;
  } else {                                       // fc3 (64x64)
    int idx = g - 81920; k = idx >> 6; n = idx & 63;
    w = f3w[idx];
    base = wp + WP_FC3;
    int ksp = k >> 5, nt = n >> 4;
    fr_hi = ksp * 4 + nt; fr_lo = (2 + ksp) * 4 + nt;
  }
  u16 hi = f2bf(w);
  u16 lo = f2bf(w - bf2f(hi));
  int lane = (n & 15) | (((k & 31) >> 3) << 4);
  int j = k & 7;
  base[fr_hi * 512 + lane * 8 + j] = hi;
  base[fr_lo * 512 + lane * 8 + j] = lo;
}

// ---- fused var+con init (MFMA) + cnt zeroing + layer-0 gate --------------
__global__ __launch_bounds__(256) void k_init(
    const float* __restrict__ vf, const float* __restrict__ cf,
    const int* __restrict__ avar, const int* __restrict__ acon,
    const float* __restrict__ vw1, const float* __restrict__ vb1, const float* __restrict__ vb2,
    const float* __restrict__ cw1, const float* __restrict__ cb1, const float* __restrict__ cb2,
    const u16* __restrict__ wp, u16* __restrict__ x0, int* __restrict__ cnt,
    const float* __restrict__ ef, const float* __restrict__ gb1,
    const float* __restrict__ gw2, const float* __restrict__ gb2,
    float* __restrict__ va0)
{
  for (int i = blockIdx.x * 256 + threadIdx.x; i < NNODE; i += gridDim.x * 256) cnt[i] = 0;

  const bool isVar = blockIdx.x < VAR_BLOCKS;
  const int bbase = isVar ? blockIdx.x : (blockIdx.x - VAR_BLOCKS);
  const int nItems = isVar ? NVAR : NCON;
  const int KD = isVar ? 62 : 63;
  const float* in  = isVar ? vf : cf;
  const int*   asc = isVar ? avar : acon;
  const float* w1  = isVar ? vw1 : cw1;
  const float* b1  = isVar ? vb1 : cb1;
  const float* b2  = isVar ? vb2 : cb2;
  const u16*   src = wp + (isVar ? WP_VARW2 : WP_CONW2);

  __shared__ u16 sB[16 * 512];
  __shared__ u16 sX[4][32 * XPAD];   // bf16 x0 rows for gate repack
  __shared__ float sw1[64], sb1[64], sb2[64];
  {
    const uint4* s4 = reinterpret_cast<const uint4*>(src);
    uint4* d4 = reinterpret_cast<uint4*>(sB);
    for (int i = threadIdx.x; i < 1024; i += 256) d4[i] = s4[i];
  }
  if (threadIdx.x < 64) {
    int t = threadIdx.x;
    sw1[t] = (t < KD) ? w1[t] : 0.f;
    sb1[t] = (t < KD) ? b1[t] : 0.f;
    sb2[t] = (t < KD) ? b2[t] : 0.f;
  }
  __syncthreads();

  int wid = threadIdx.x >> 6, lane = threadIdx.x & 63;
  long ib = ((long)bbase * 4 + wid) * 32;
  if (ib >= nItems) return;     // whole-wave exit (nItems % 32 == 0)
  int l15 = lane & 15, lg = lane >> 4;

  float w1r[16], b1r[16];
#pragma unroll
  for (int ks = 0; ks < 2; ++ks)
#pragma unroll
    for (int j = 0; j < 8; ++j) {
      int k = 32 * ks + 8 * lg + j;
      w1r[ks * 8 + j] = sw1[k]; b1r[ks * 8 + j] = sb1[k];
    }

  float v0 = in[ib + l15], v1 = in[ib + 16 + l15];
  frag8 hh[2][2], hl[2][2];
#pragma unroll
  for (int np = 0; np < 2; ++np) {
    float v = np ? v1 : v0;
#pragma unroll
    for (int ks = 0; ks < 2; ++ks) {
      frag8 th, tl;
#pragma unroll
      for (int j = 0; j < 8; ++j) {
        float h = fmaxf(fmaf(v, w1r[ks * 8 + j], b1r[ks * 8 + j]), 0.f);
        u16 hi = f2bf(h);
        u16 lo = f2bf(h - bf2f(hi));
        th[j] = (short)hi; tl[j] = (short)lo;
      }
      hh[np][ks] = th; hl[np][ks] = tl;
    }
  }

  const f32x4 z = {0.f, 0.f, 0.f, 0.f};
  f32x4 acc[4][2];
#pragma unroll
  for (int m = 0; m < 4; ++m)
#pragma unroll
    for (int np = 0; np < 2; ++np) acc[m][np] = z;

#pragma unroll
  for (int ks = 0; ks < 2; ++ks)
#pragma unroll
    for (int m = 0; m < 4; ++m) {
      frag8 bh = *reinterpret_cast<const frag8*>(&sB[((ks * 4 + m) * 512) + lane * 8]);
      frag8 bl = *reinterpret_cast<const frag8*>(&sB[(((2 + ks) * 4 + m) * 512) + lane * 8]);
#pragma unroll
      for (int np = 0; np < 2; ++np) {
        acc[m][np] = __builtin_amdgcn_mfma_f32_16x16x32_bf16(bh, hh[np][ks], acc[m][np], 0, 0, 0);
        acc[m][np] = __builtin_amdgcn_mfma_f32_16x16x32_bf16(bh, hl[np][ks], acc[m][np], 0, 0, 0);
        acc[m][np] = __builtin_amdgcn_mfma_f32_16x16x32_bf16(bl, hh[np][ks], acc[m][np], 0, 0, 0);
      }
    }

  long rsave[2];
#pragma unroll
  for (int np = 0; np < 2; ++np) {
    long r = asc[ib + 16 * np + l15];
    rsave[np] = r;
    float vv = np ? v1 : v0;
    u16* orow = x0 + r * 64;
#pragma unroll
    for (int m = 0; m < 4; ++m) {
      float o[4];
#pragma unroll
      for (int rr = 0; rr < 4; ++rr) o[rr] = acc[m][np][rr] + sb2[16 * m + 4 * lg + rr];
      if (m == 3 && lg == 3) {
        if (isVar) { o[2] = vv; o[3] = 1.0f; } else { o[3] = vv; }
      }
      u32 p0 = (u32)f2bf(o[0]) | ((u32)f2bf(o[1]) << 16);
      u32 p1 = (u32)f2bf(o[2]) | ((u32)f2bf(o[3]) << 16);
      *reinterpret_cast<uint2*>(orow + 16 * m + 4 * lg) = make_uint2(p0, p1);
      *reinterpret_cast<uint2*>(&sX[wid][(np * 16 + l15) * XPAD + 16 * m + 4 * lg]) =
          make_uint2(p0, p1);
    }
  }
  asm volatile("s_waitcnt lgkmcnt(0)" ::: "memory");

  // ---- layer-0 gate on x0 (bit-exact vs reading back the stored bf16) ----
  const u16* wg = wp + WP_NODE(0);
  f32x4 accg[4][2];
#pragma unroll
  for (int m = 0; m < 4; ++m)
#pragma unroll
    for (int np = 0; np < 2; ++np) accg[m][np] = z;
#pragma unroll
  for (int ks = 0; ks < 2; ++ks) {
    frag8 xg0 = *reinterpret_cast<const frag8*>(&sX[wid][(0 * 16 + l15) * XPAD + ks * 32 + 8 * lg]);
    frag8 xg1 = *reinterpret_cast<const frag8*>(&sX[wid][(1 * 16 + l15) * XPAD + ks * 32 + 8 * lg]);
#pragma unroll
    for (int m = 0; m < 4; ++m) {
      frag8 wh = *reinterpret_cast<const frag8*>(&wg[((ks * 4 + m) * 512) + lane * 8]);
      frag8 wl = *reinterpret_cast<const frag8*>(&wg[(((2 + ks) * 4 + m) * 512) + lane * 8]);
      accg[m][0] = __builtin_amdgcn_mfma_f32_16x16x32_bf16(wh, xg0, accg[m][0], 0, 0, 0);
      accg[m][0] = __builtin_amdgcn_mfma_f32_16x16x32_bf16(wl, xg0, accg[m][0], 0, 0, 0);
      accg[m][1] = __builtin_amdgcn_mfma_f32_16x16x32_bf16(wh, xg1, accg[m][1], 0, 0, 0);
      accg[m][1] = __builtin_amdgcn_mfma_f32_16x16x32_bf16(wl, xg1, accg[m][1], 0, 0, 0);
    }
  }
  float b2v = gb2[0];
#pragma unroll
  for (int np = 0; np < 2; ++np) {
    float p = 0.f;
#pragma unroll
    for (int m = 0; m < 4; ++m) {
      f32x4 b1v = *reinterpret_cast<const f32x4*>(gb1 + 16 * m + 4 * lg);
      f32x4 w2v = *reinterpret_cast<const f32x4*>(gw2 + 16 * m + 4 * lg);
#pragma unroll
      for (int r = 0; r < 4; ++r)
        p += sigmoidf_(accg[m][np][r] + b1v[r]) * w2v[r];
    }
    p += __shfl_xor(p, 16);
    p += __shfl_xor(p, 32);
    if (lane < 16) va0[rsave[np]] = (p + b2v) * ef[rsave[np]];
  }
}

// ---- CSR-ish bucket build: slots[d][pos] = src | (type<<20) --------------
__global__ __launch_bounds__(256) void k_scatter(
    const int* __restrict__ src, const int* __restrict__ dst,
    const int* __restrict__ et, int* __restrict__ cnt, int* __restrict__ slots)
{
  int e = blockIdx.x * 256 + threadIdx.x;
  if (e >= NEDGE) return;
  int d = dst[e];
  int pos = atomicAdd(&cnt[d], 1);
  if (pos < SLOTCAP) slots[d * SLOTCAP + pos] = src[e] | ((et[e] & 1) << 20);
}

// ---- per-layer fused aggregate+transform + NEXT-layer gate ---------------
// Lane (p,q): node = nb+p, owns features {ks*32+8q..+7} of S0 (ks=0,1) and S1.
// xout[dst] = relu([S0|S1]@[Wc_pad;Wv] + add-patch(col62+=S0[62], col63+=Sva) + b)
// then va_next[dst] = (sigmoid(xout@W1_next+b1).w2+b2)*ef[dst]  (if w1g)
__global__ __launch_bounds__(256) void k_aggr2(
    const u16* __restrict__ x, const float* __restrict__ va,
    const int* __restrict__ cnt, const int* __restrict__ slots,
    const u16* __restrict__ wsrc,     // WCV frags (32 x 512): hi 0..15, lo 16..31
    const float* __restrict__ bias, u16* __restrict__ xout,
    const u16* __restrict__ w1g,      // next-layer W1 frags (or null)
    const float* __restrict__ gb1, const float* __restrict__ gw2,
    const float* __restrict__ gb2, const float* __restrict__ ef,
    float* __restrict__ va_next)
{
  __shared__ u16 sX[4][16 * XPAD];    // 8.7 KB: xout rows for gate repack
  int wid = threadIdx.x >> 6, lane = threadIdx.x & 63;
  int q = lane >> 4, p = lane & 15;
  int nb = (blockIdx.x * 4 + wid) * 16;
  int node = nb + p;
  bool active = (node < NNODE);

  float a0[16], a1[16];
#pragma unroll
  for (int i = 0; i < 16; ++i) { a0[i] = 0.f; a1[i] = 0.f; }
  float sva = 0.f;

  if (active) {
    int deg = cnt[node]; if (deg > SLOTCAP) deg = SLOTCAP;
    const int* sl = slots + (size_t)node * SLOTCAP;
#pragma unroll 1
    for (int j0 = 0; j0 < deg; j0 += 4) {
      int4 sv = *reinterpret_cast<const int4*>(sl + j0);   // 16B-aligned
#pragma unroll
      for (int k = 0; k < 4; ++k) {
        int v = (k == 0) ? sv.x : (k == 1) ? sv.y : (k == 2) ? sv.z : sv.w;
        bool ok = (j0 + k < deg);
        int s = ok ? (v & 0xFFFFF) : 0;
        int t = (v >> 20) & 1;
        const u16* xr = x + (size_t)s * 64 + 8 * q;
        uint4 r0 = *reinterpret_cast<const uint4*>(xr);
        uint4 r1 = *reinterpret_cast<const uint4*>(xr + 32);
        float vg = va[s];
        float m0 = (ok && t == 0) ? 1.f : 0.f;
        float m1 = (ok && t != 0) ? 1.f : 0.f;
        float f[16] = {cvlo(r0.x), cvhi(r0.x), cvlo(r0.y), cvhi(r0.y),
                       cvlo(r0.z), cvhi(r0.z), cvlo(r0.w), cvhi(r0.w),
                       cvlo(r1.x), cvhi(r1.x), cvlo(r1.y), cvhi(r1.y),
                       cvlo(r1.z), cvhi(r1.z), cvlo(r1.w), cvhi(r1.w)};
#pragma unroll
        for (int i = 0; i < 16; ++i) {
          a0[i] = fmaf(f[i], m0, a0[i]);
          a1[i] = fmaf(f[i], m1, a1[i]);
        }
        sva = fmaf(vg, m0, sva);
      }
    }
  }

  float s62 = a0[14];   // feature 62 lives on q==3 (ks=1, j=6)

  frag8 sh[4], sl_[4];
#pragma unroll
  for (int ks = 0; ks < 2; ++ks)
#pragma unroll
    for (int j = 0; j < 8; ++j) {
      float v0 = a0[ks * 8 + j];
      u16 h0 = f2bf(v0);
      sh[ks][j] = (short)h0; sl_[ks][j] = (short)f2bf(v0 - bf2f(h0));
      float v1 = a1[ks * 8 + j];
      u16 h1 = f2bf(v1);
      sh[2 + ks][j] = (short)h1; sl_[2 + ks][j] = (short)f2bf(v1 - bf2f(h1));
    }

  const f32x4 z = {0.f, 0.f, 0.f, 0.f};
  f32x4 acc[4];
#pragma unroll
  for (int m = 0; m < 4; ++m) acc[m] = z;
#pragma unroll
  for (int ks = 0; ks < 4; ++ks)
#pragma unroll
    for (int m = 0; m < 4; ++m) {
      frag8 wh = *reinterpret_cast<const frag8*>(&wsrc[((ks * 4 + m) * 512) + lane * 8]);
      frag8 wl = *reinterpret_cast<const frag8*>(&wsrc[((16 + ks * 4 + m) * 512) + lane * 8]);
      acc[m] = __builtin_amdgcn_mfma_f32_16x16x32_bf16(wh, sh[ks],  acc[m], 0, 0, 0);
      acc[m] = __builtin_amdgcn_mfma_f32_16x16x32_bf16(wh, sl_[ks], acc[m], 0, 0, 0);
      acc[m] = __builtin_amdgcn_mfma_f32_16x16x32_bf16(wl, sh[ks],  acc[m], 0, 0, 0);
    }

  // epilogue: store xout (guarded) + LDS repack rows (all lanes)
  u16* orow = xout + (size_t)node * 64;
#pragma unroll
  for (int m = 0; m < 4; ++m) {
    f32x4 bv = *reinterpret_cast<const f32x4*>(bias + 16 * m + 4 * q);
    float o[4];
#pragma unroll
    for (int r = 0; r < 4; ++r) o[r] = acc[m][r] + bv[r];
    if (m == 3 && q == 3) { o[2] += s62; o[3] += sva; }   // ADDITIVE patch
    u32 p0 = (u32)f2bf(fmaxf(o[0], 0.f)) | ((u32)f2bf(fmaxf(o[1], 0.f)) << 16);
    u32 p1 = (u32)f2bf(fmaxf(o[2], 0.f)) | ((u32)f2bf(fmaxf(o[3], 0.f)) << 16);
    if (active)
      *reinterpret_cast<uint2*>(orow + 16 * m + 4 * q) = make_uint2(p0, p1);
    *reinterpret_cast<uint2*>(&sX[wid][p * XPAD + 16 * m + 4 * q]) = make_uint2(p0, p1);
  }

  if (w1g == nullptr) return;
  asm volatile("s_waitcnt lgkmcnt(0)" ::: "memory");

  // ---- next-layer gate on xout (bit-exact vs re-reading stored bf16) -----
  f32x4 accg[4];
#pragma unroll
  for (int m = 0; m < 4; ++m) accg[m] = z;
#pragma unroll
  for (int ks = 0; ks < 2; ++ks) {
    frag8 xg = *reinterpret_cast<const frag8*>(&sX[wid][p * XPAD + ks * 32 + 8 * q]);
#pragma unroll
    for (int m = 0; m < 4; ++m) {
      frag8 wh = *reinterpret_cast<const frag8*>(&w1g[((ks * 4 + m) * 512) + lane * 8]);
      frag8 wl = *reinterpret_cast<const frag8*>(&w1g[(((2 + ks) * 4 + m) * 512) + lane * 8]);
      accg[m] = __builtin_amdgcn_mfma_f32_16x16x32_bf16(wh, xg, accg[m], 0, 0, 0);
      accg[m] = __builtin_amdgcn_mfma_f32_16x16x32_bf16(wl, xg, accg[m], 0, 0, 0);
    }
  }
  float pg = 0.f;
#pragma unroll
  for (int m = 0; m < 4; ++m) {
    f32x4 b1v = *reinterpret_cast<const f32x4*>(gb1 + 16 * m + 4 * q);
    f32x4 w2v = *reinterpret_cast<const f32x4*>(gw2 + 16 * m + 4 * q);
#pragma unroll
    for (int r = 0; r < 4; ++r)
      pg += sigmoidf_(accg[m][r] + b1v[r]) * w2v[r];
  }
  pg += __shfl_xor(pg, 16);
  pg += __shfl_xor(pg, 32);
  if (lane < 16 && nb + lane < NNODE) {
    int n2 = nb + lane;
    va_next[n2] = (pg + gb2[0]) * ef[n2];
  }
}

// ---- head fc1: [NVAR,320]@[320,64] transposed MFMA, 2 LDS phases ---------
__global__ __launch_bounds__(256) void k_head1(
    const u16* __restrict__ xs, const int* __restrict__ assoc,
    const u16* __restrict__ wp, const float* __restrict__ fb,
    u16* __restrict__ ohi, u16* __restrict__ olo)
{
  __shared__ u16 sB[40 * 512];
  __shared__ float sfb[64];
  if (threadIdx.x < 64) sfb[threadIdx.x] = fb[threadIdx.x];

  int wid = threadIdx.x >> 6, lane = threadIdx.x & 63;
  long ib = ((long)blockIdx.x * 4 + wid) * 32;
  bool act = (ib < NVAR);
  int l15 = lane & 15, lg = lane >> 4;
  long node0 = 0, node1 = 0;
  if (act) { node0 = assoc[ib + l15]; node1 = assoc[ib + 16 + l15]; }

  const f32x4 z = {0.f, 0.f, 0.f, 0.f};
  f32x4 acc[4][2];
#pragma unroll
  for (int m = 0; m < 4; ++m)
#pragma unroll
    for (int np = 0; np < 2; ++np) acc[m][np] = z;

#pragma unroll 1
  for (int ph = 0; ph < 2; ++ph) {
    __syncthreads();
    {
      const uint4* s4 = reinterpret_cast<const uint4*>(wp + WP_FC1(ph));
      uint4* d4 = reinterpret_cast<uint4*>(sB);
      for (int i = threadIdx.x; i < 2560; i += 256) d4[i] = s4[i];
    }
    __syncthreads();
    if (!act) continue;
#pragma unroll
    for (int ks = 0; ks < 5; ++ks) {
      int kg = ph * 160 + ks * 32;
      int pl = kg >> 6, c = (kg & 63) + 8 * lg;
      frag8 a0 = *reinterpret_cast<const frag8*>(xs + ((size_t)pl * NNODE + node0) * 64 + c);
      frag8 a1 = *reinterpret_cast<const frag8*>(xs + ((size_t)pl * NNODE + node1) * 64 + c);
#pragma unroll
      for (int m = 0; m < 4; ++m) {
        frag8 bh = *reinterpret_cast<const frag8*>(&sB[((ks * 4 + m) * 512) + lane * 8]);
        frag8 bl = *reinterpret_cast<const frag8*>(&sB[(((5 + ks) * 4 + m) * 512) + lane * 8]);
        acc[m][0] = __builtin_amdgcn_mfma_f32_16x16x32_bf16(bh, a0, acc[m][0], 0, 0, 0);
        acc[m][0] = __builtin_amdgcn_mfma_f32_16x16x32_bf16(bl, a0, acc[m][0], 0, 0, 0);
        acc[m][1] = __builtin_amdgcn_mfma_f32_16x16x32_bf16(bh, a1, acc[m][1], 0, 0, 0);
        acc[m][1] = __builtin_amdgcn_mfma_f32_16x16x32_bf16(bl, a1, acc[m][1], 0, 0, 0);
      }
    }
  }
  if (!act) return;
#pragma unroll
  for (int np = 0; np < 2; ++np) {
    size_t row = (size_t)(ib + 16 * np + l15) * 64;
#pragma unroll
    for (int m = 0; m < 4; ++m) {
      u16 hi[4], lo[4];
#pragma unroll
      for (int r = 0; r < 4; ++r) {
        float v = fmaxf(acc[m][np][r] + sfb[16 * m + 4 * lg + r], 0.f);
        hi[r] = f2bf(v);
        lo[r] = f2bf(v - bf2f(hi[r]));
      }
      size_t o = row + 16 * m + 4 * lg;
      *reinterpret_cast<uint2*>(ohi + o) =
          make_uint2((u32)hi[0] | ((u32)hi[1] << 16), (u32)hi[2] | ((u32)hi[3] << 16));
      *reinterpret_cast<uint2*>(olo + o) =
          make_uint2((u32)lo[0] | ((u32)lo[1] << 16), (u32)lo[2] | ((u32)lo[3] << 16));
    }
  }
}

// ---- head fc2: relu([NVAR,64]@[64,64]+b), transposed MFMA ----------------
__global__ __launch_bounds__(256) void k_dense64(
    const u16* __restrict__ ahi, const u16* __restrict__ alo,
    const u16* __restrict__ wsrc, const float* __restrict__ b,
    u16* __restrict__ ohi, u16* __restrict__ olo)
{
  __shared__ u16 sB[16 * 512];
  __shared__ float sbv[64];
  {
    const uint4* s4 = reinterpret_cast<const uint4*>(wsrc);
    uint4* d4 = reinterpret_cast<uint4*>(sB);
    for (int i = threadIdx.x; i < 1024; i += 256) d4[i] = s4[i];
  }
  if (threadIdx.x < 64) sbv[threadIdx.x] = b[threadIdx.x];
  __syncthreads();

  int wid = threadIdx.x >> 6, lane = threadIdx.x & 63;
  long ib = ((long)blockIdx.x * 4 + wid) * 32;
  if (ib >= NVAR) return;
  int l15 = lane & 15, lg = lane >> 4;

  frag8 xh[2][2], xl[2][2];
#pragma unroll
  for (int np = 0; np < 2; ++np) {
    const u16* bh_ = ahi + (ib + 16 * np + l15) * 64 + 8 * lg;
    const u16* bl_ = alo + (ib + 16 * np + l15) * 64 + 8 * lg;
    xh[np][0] = *reinterpret_cast<const frag8*>(bh_);
    xh[np][1] = *reinterpret_cast<const frag8*>(bh_ + 32);
    xl[np][0] = *reinterpret_cast<const frag8*>(bl_);
    xl[np][1] = *reinterpret_cast<const frag8*>(bl_ + 32);
  }

  const f32x4 z = {0.f, 0.f, 0.f, 0.f};
  f32x4 acc[4][2];
#pragma unroll
  for (int m = 0; m < 4; ++m)
#pragma unroll
    for (int np = 0; np < 2; ++np) acc[m][np] = z;

#pragma unroll
  for (int ks = 0; ks < 2; ++ks)
#pragma unroll
    for (int m = 0; m < 4; ++m) {
      frag8 bh = *reinterpret_cast<const frag8*>(&sB[((ks * 4 + m) * 512) + lane * 8]);
      frag8 bl = *reinterpret_cast<const frag8*>(&sB[(((2 + ks) * 4 + m) * 512) + lane * 8]);
#pragma unroll
      for (int np = 0; np < 2; ++np) {
        acc[m][np] = __builtin_amdgcn_mfma_f32_16x16x32_bf16(bh, xh[np][ks], acc[m][np], 0, 0, 0);
        acc[m][np] = __builtin_amdgcn_mfma_f32_16x16x32_bf16(bh, xl[np][ks], acc[m][np], 0, 0, 0);
        acc[m][np] = __builtin_amdgcn_mfma_f32_16x16x32_bf16(bl, xh[np][ks], acc[m][np], 0, 0, 0);
      }
    }

#pragma unroll
  for (int np = 0; np < 2; ++np) {
    size_t row = (size_t)(ib + 16 * np + l15) * 64;
#pragma unroll
    for (int m = 0; m < 4; ++m) {
      u16 hi[4], lo[4];
#pragma unroll
      for (int r = 0; r < 4; ++r) {
        float v = fmaxf(acc[m][np][r] + sbv[16 * m + 4 * lg + r], 0.f);
        hi[r] = f2bf(v);
        lo[r] = f2bf(v - bf2f(hi[r]));
      }
      size_t o = row + 16 * m + 4 * lg;
      *reinterpret_cast<uint2*>(ohi + o) =
          make_uint2((u32)hi[0] | ((u32)hi[1] << 16), (u32)hi[2] | ((u32)hi[3] << 16));
      *reinterpret_cast<uint2*>(olo + o) =
          make_uint2((u32)lo[0] | ((u32)lo[1] << 16), (u32)lo[2] | ((u32)lo[3] << 16));
    }
  }
}

// ---- head fc3+fc4 fused: out = relu(h@W3+b3)@w4 + b4 ---------------------
__global__ __launch_bounds__(256) void k_dense64o(
    const u16* __restrict__ ahi, const u16* __restrict__ alo,
    const u16* __restrict__ wsrc, const float* __restrict__ b,
    const float* __restrict__ w4, const float* __restrict__ b4,
    float* __restrict__ out)
{
  __shared__ u16 sB[16 * 512];
  __shared__ float sbv[64], sw4[64];
  {
    const uint4* s4 = reinterpret_cast<const uint4*>(wsrc);
    uint4* d4 = reinterpret_cast<uint4*>(sB);
    for (int i = threadIdx.x; i < 1024; i += 256) d4[i] = s4[i];
  }
  if (threadIdx.x < 64) {
    sbv[threadIdx.x] = b[threadIdx.x];
    sw4[threadIdx.x] = w4[threadIdx.x];
  }
  __syncthreads();

  int wid = threadIdx.x >> 6, lane = threadIdx.x & 63;
  long ib = ((long)blockIdx.x * 4 + wid) * 32;
  if (ib >= NVAR) return;   // whole-wave exit (NVAR % 32 == 0)
  int l15 = lane & 15, lg = lane >> 4;

  frag8 xh[2][2], xl[2][2];
#pragma unroll
  for (int np = 0; np < 2; ++np) {
    const u16* bh_ = ahi + (ib + 16 * np + l15) * 64 + 8 * lg;
    const u16* bl_ = alo + (ib + 16 * np + l15) * 64 + 8 * lg;
    xh[np][0] = *reinterpret_cast<const frag8*>(bh_);
    xh[np][1] = *reinterpret_cast<const frag8*>(bh_ + 32);
    xl[np][0] = *reinterpret_cast<const frag8*>(bl_);
    xl[np][1] = *reinterpret_cast<const frag8*>(bl_ + 32);
  }

  const f32x4 z = {0.f, 0.f, 0.f, 0.f};
  f32x4 acc[4][2];
#pragma unroll
  for (int m = 0; m < 4; ++m)
#pragma unroll
    for (int np = 0; np < 2; ++np) acc[m][np] = z;

#pragma unroll
  for (int ks = 0; ks < 2; ++ks)
#pragma unroll
    for (int m = 0; m < 4; ++m) {
      frag8 bh = *reinterpret_cast<const frag8*>(&sB[((ks * 4 + m) * 512) + lane * 8]);
      frag8 bl = *reinterpret_cast<const frag8*>(&sB[(((2 + ks) * 4 + m) * 512) + lane * 8]);
#pragma unroll
      for (int np = 0; np < 2; ++np) {
        acc[m][np] = __builtin_amdgcn_mfma_f32_16x16x32_bf16(bh, xh[np][ks], acc[m][np], 0, 0, 0);
        acc[m][np] = __builtin_amdgcn_mfma_f32_16x16x32_bf16(bh, xl[np][ks], acc[m][np], 0, 0, 0);
        acc[m][np] = __builtin_amdgcn_mfma_f32_16x16x32_bf16(bl, xh[np][ks], acc[m][np], 0, 0, 0);
      }
    }

  float partial[2] = {0.f, 0.f};
#pragma unroll
  for (int np = 0; np < 2; ++np)
#pragma unroll
    for (int m = 0; m < 4; ++m)
#pragma unroll
      for (int r = 0; r < 4; ++r) {
        float v = fmaxf(acc[m][np][r] + sbv[16 * m + 4 * lg + r], 0.f);
        partial[np] = fmaf(v, sw4[16 * m + 4 * lg + r], partial[np]);
      }
#pragma unroll
  for (int np = 0; np < 2; ++np) {
    partial[np] += __shfl_xor(partial[np], 16);
    partial[np] += __shfl_xor(partial[np], 32);
  }
  if (lane < 16) {
    float b4v = b4[0];
    out[ib + lane] = partial[0] + b4v;
    out[ib + 16 + lane] = partial[1] + b4v;
  }
}

// ---- launch --------------------------------------------------------------
extern "C" void kernel_launch(void* const* d_in, const int* in_sizes, int n_in,
                              void* d_out, int out_size, void* d_ws, size_t ws_size,
                              hipStream_t stream)
{
  (void)in_sizes; (void)n_in; (void)out_size; (void)ws_size;
  const float* var_nf = (const float*)d_in[0];
  const float* con_nf = (const float*)d_in[1];
  const float* edge_f = (const float*)d_in[2];
  const int*   eidx   = (const int*)d_in[3];
  const int*   etyp   = (const int*)d_in[4];
  const int*   avar   = (const int*)d_in[5];
  const int*   acon   = (const int*)d_in[6];
  const float* vw1 = (const float*)d_in[7];
  const float* vb1 = (const float*)d_in[8];
  const float* vw2 = (const float*)d_in[9];
  const float* vb2 = (const float*)d_in[10];
  const float* cw1 = (const float*)d_in[11];
  const float* cb1 = (const float*)d_in[12];
  const float* cw2 = (const float*)d_in[13];
  const float* cb2 = (const float*)d_in[14];
  const float* hw1 = (const float*)d_in[15];
  const float* hb1 = (const float*)d_in[16];
  const float* hw2 = (const float*)d_in[17];
  const float* hb2 = (const float*)d_in[18];
  const float* wco = (const float*)d_in[19];
  const float* wva = (const float*)d_in[20];
  const float* bia = (const float*)d_in[21];
  const float* f1w = (const float*)d_in[22];
  const float* f1b = (const float*)d_in[23];
  const float* f2w = (const float*)d_in[24];
  const float* f2b = (const float*)d_in[25];
  const float* f3w = (const float*)d_in[26];
  const float* f3b = (const float*)d_in[27];
  const float* f4w = (const float*)d_in[28];
  const float* f4b = (const float*)d_in[29];

  char* ws = (char*)d_ws;
  // xs [0,64M) | cnt [64M,+0.4M) | slots [64.4M,+12.8M) | va0 [77.2M,+0.4M)
  // | va1 [77.6M,+0.4M) | wp [78.0M,+0.35M) | head planes [78.4M ..)
  u16*   xs    = (u16*)ws;
  int*   cnt   = (int*)(ws + 64000000);
  int*   slots = (int*)(ws + 64400000);
  float* va0   = (float*)(ws + 77200000);
  float* va1   = (float*)(ws + 77600000);
  u16*   wp    = (u16*)(ws + 78000000);
  u16* hAhi = (u16*)(ws + 78400000);
  u16* hAlo = (u16*)(ws + 86080000);
  u16* hBhi = (u16*)(ws + 93760000);
  u16* hBlo = (u16*)(ws + 101440000);

  const int* esrc = eidx;
  const int* edst = eidx + NEDGE;

  k_prep<<<PREP_TOTAL / 256, 256, 0, stream>>>(hw1, wco, wva, vw2, cw2, f1w, f2w, f3w, wp);
  k_init<<<VAR_BLOCKS + CON_BLOCKS, 256, 0, stream>>>(
      var_nf, con_nf, avar, acon, vw1, vb1, vb2, cw1, cb1, cb2, wp, xs, cnt,
      edge_f, hb1, hw2, hb2, va0);
  k_scatter<<<(NEDGE + 255) / 256, 256, 0, stream>>>(esrc, edst, etyp, cnt, slots);

  for (int l = 0; l < 4; ++l) {
    u16* xin  = xs + (size_t)l * NNODE * 64;
    u16* xout = xs + (size_t)(l + 1) * NNODE * 64;
    float* va_in  = (l & 1) ? va1 : va0;
    float* va_out = (l & 1) ? va0 : va1;
    bool hasGate = (l < 3);
    k_aggr2<<<(NNODE + 63) / 64, 256, 0, stream>>>(
        xin, va_in, cnt, slots, wp + WP_NODE(l) + 16 * 512, bia + l * 64, xout,
        hasGate ? (wp + WP_NODE(l + 1)) : nullptr,
        hasGate ? (hb1 + (l + 1) * 64) : nullptr,
        hasGate ? (hw2 + (l + 1) * 64) : nullptr,
        hasGate ? (hb2 + (l + 1)) : nullptr,
        edge_f, va_out);
  }

  k_head1<<<(NVAR + 127) / 128, 256, 0, stream>>>(xs, avar, wp, f1b, hAhi, hAlo);
  k_dense64<<<(NVAR + 127) / 128, 256, 0, stream>>>(hAhi, hAlo, wp + WP_FC2, f2b, hBhi, hBlo);
  k_dense64o<<<(NVAR + 127) / 128, 256, 0, stream>>>(hBhi, hBlo, wp + WP_FC3, f3b, f4w, f4b,
                                                     (float*)d_out);
}